// Round 23
// baseline (526.188 us; speedup 1.0000x reference)
//
#include <hip/hip_runtime.h>
#include <math.h>

#define DIM 66
#define NPATH 17
#define WNUM 648
#define NHID 32
#define HPAD 40   // Hlds halves per edge (80B stride, 16B-aligned b128)
#define WROWS 656 // 648 rounded to 16

typedef _Float16 f16x8 __attribute__((ext_vector_type(8)));
typedef float f32x4 __attribute__((ext_vector_type(4)));

// ---------------- CG computation (device, mirrors reference exactly) ----------------

__device__ double dfact(int n){ double f=1.0; for(int i=2;i<=n;i++) f*=(double)i; return f; }

__device__ double su2_cg(int j1,int j2,int j3,int m1,int m2,int m3){
  if(m1+m2!=m3) return 0.0;
  double pre = sqrt((double)(2*j3+1)*dfact(j3+j1-j2)*dfact(j3-j1+j2)*dfact(j1+j2-j3)/dfact(j1+j2+j3+1));
  pre *= sqrt(dfact(j3+m3)*dfact(j3-m3)*dfact(j1-m1)*dfact(j1+m1)*dfact(j2-m2)*dfact(j2+m2));
  double s=0.0;
  for(int k=0;k<=j1+j2-j3;k++){
    int a0=k, a1=j1+j2-j3-k, a2=j1-m1-k, a3=j2+m2-k, a4=j3-j2+m1+k, a5=j3-j1-m2+k;
    if(a0<0||a1<0||a2<0||a3<0||a4<0||a5<0) continue;
    double d = dfact(a0)*dfact(a1)*dfact(a2)*dfact(a3)*dfact(a4)*dfact(a5);
    s += ((k&1)? -1.0:1.0)/d;
  }
  return pre*s;
}

__device__ void u_real_entry(int l, int row, int col, double& re, double& im){
  re=0.0; im=0.0;
  const double sq = 0.7071067811865476;
  int m = row - l;
  if(m>0){
    if(col==l+m) re = ((m&1)? -sq : sq);
    else if(col==l-m) re = sq;
  } else if(m==0){
    if(col==l) re = 1.0;
  } else {
    int am = -m;
    if(col==l+m) im = sq;
    else if(col==l-m) im = ((am&1)? sq : -sq);
  }
}

__constant__ int c_l1[NPATH]   = {0,0,0,1,1,1,1,1,1,1,1,1,2,2,2,2,2};
__constant__ int c_l2[NPATH]   = {0,1,2,0,1,1,1,2,0,1,2,2,0,1,2,2,2};
__constant__ int c_l3[NPATH]   = {0,1,2,1,0,1,2,1,1,1,1,2,2,1,0,1,2};
__constant__ int c_cgoff[NPATH]= {0,1,10,35,44,53,80,125,170,179,206,251,326,351,396,421,496};

__global__ void cg_init_kernel(float* __restrict__ cg_out){
  int p = blockIdx.x;
  int l1=c_l1[p], l2=c_l2[p], l3=c_l3[p];
  int n1=2*l1+1, n2=2*l2+1, n3=2*l3+1;
  int ntot=n1*n2*n3;
  __shared__ double Cc[125];
  __shared__ double red[128];
  int t=threadIdx.x;
  if(t<ntot){
    int i=t/(n2*n3), j=(t/n3)%n2, k=t%n3;
    Cc[t] = su2_cg(l1,l2,l3,i-l1,j-l2,k-l3);
  }
  __syncthreads();
  double Tre=0.0, Tim=0.0;
  if(t<ntot){
    int a=t/(n2*n3), b=(t/n3)%n2, c=t%n3;
    for(int i=0;i<n1;i++)for(int j=0;j<n2;j++)for(int k=0;k<n3;k++){
      double cc=Cc[(i*n2+j)*n3+k];
      if(cc==0.0) continue;
      double u1r,u1i,u2r,u2i,u3r,u3i;
      u_real_entry(l1,a,i,u1r,u1i); u1i=-u1i;
      u_real_entry(l2,b,j,u2r,u2i); u2i=-u2i;
      u_real_entry(l3,c,k,u3r,u3i);
      double pr=u1r*u2r-u1i*u2i, pi=u1r*u2i+u1i*u2r;
      double qr=pr*u3r-pi*u3i,   qi=pr*u3i+pi*u3r;
      Tre+=qr*cc; Tim+=qi*cc;
    }
  }
  red[t]=fabs(Tre); __syncthreads();
  for(int s=64;s>0;s>>=1){ if(t<s) red[t]+=red[t+s]; __syncthreads(); }
  double sar=red[0]; __syncthreads();
  red[t]=fabs(Tim); __syncthreads();
  for(int s=64;s>0;s>>=1){ if(t<s) red[t]+=red[t+s]; __syncthreads(); }
  double sai=red[0]; __syncthreads();
  double chosen = (sar>=sai)? Tre : Tim;
  red[t]=chosen*chosen; __syncthreads();
  for(int s=64;s>0;s>>=1){ if(t<s) red[t]+=red[t+s]; __syncthreads(); }
  double nrm=sqrt(red[0]);
  if(t<ntot) cg_out[c_cgoff[p]+t] = (float)(chosen/nrm);
}

// ------- W -> f16: transpose + fold 1/sqrt(32), ORIGINAL path-order rows, pad to 656 -------

__global__ void wh_pack_kernel(const float* __restrict__ w2, _Float16* __restrict__ wh){
  int i=blockIdx.x*blockDim.x+threadIdx.x;
  if(i>=WROWS*NHID) return;
  int nr=i>>5, t=i&31;
  float val = (nr<WNUM) ? w2[t*WNUM+nr]*0.17677669529663687f : 0.f; // 1/sqrt(32)
  wh[i]=(_Float16)val;
}

// ---------------- per-node linears: h_in (lin_in) to ws, res to d_out ----------------

__global__ void linear_kernel(const float* __restrict__ h,
  const float* __restrict__ w0i, const float* __restrict__ w1oi, const float* __restrict__ w1ei,
  const float* __restrict__ w2i, const float* __restrict__ b0i,
  const float* __restrict__ w0r, const float* __restrict__ w1or_, const float* __restrict__ w1er,
  const float* __restrict__ w2r, const float* __restrict__ b0r,
  float* __restrict__ h_in, float* __restrict__ out, int total)
{
  int idx=blockIdx.x*blockDim.x+threadIdx.x;
  if(idx>=total) return;
  int d = idx % DIM;
  long bn = idx / DIM;
  const float* hr = h + bn*(long)DIM;
  float s1=0.f, s2=0.f, o1, o2;
  if(d<12){
    #pragma unroll
    for(int u=0;u<12;u++){ float xv=hr[u]; s1+=xv*w0i[u*12+d]; s2+=xv*w0r[u*12+d]; }
    const float r = 0.28867513459481287f;
    o1 = s1*r + b0i[d]; o2 = s2*r + b0r[d];
  } else if(d<24){
    int rel=d-12, v=rel/3, i=rel%3;
    #pragma unroll
    for(int u=0;u<4;u++){ float xv=hr[12+u*3+i]; s1+=xv*w1oi[u*4+v]; s2+=xv*w1or_[u*4+v]; }
    o1=s1*0.5f; o2=s2*0.5f;
  } else if(d<36){
    int rel=d-24, v=rel/3, i=rel%3;
    #pragma unroll
    for(int u=0;u<4;u++){ float xv=hr[24+u*3+i]; s1+=xv*w1ei[u*4+v]; s2+=xv*w1er[u*4+v]; }
    o1=s1*0.5f; o2=s2*0.5f;
  } else {
    int rel=d-36, v=rel/5, i=rel%5;
    #pragma unroll
    for(int u=0;u<6;u++){ float xv=hr[36+u*5+i]; s1+=xv*w2i[u*6+v]; s2+=xv*w2r[u*6+v]; }
    const float r=0.4082482904638631f;
    o1=s1*r; o2=s2*r;
  }
  h_in[idx]=o1; out[idx]=o2;
}

// ---------------- Kernel A: wv[648][BE] = W_f16 @ hid_f16 via MFMA (verified R19-R22) ----------------

__global__ __launch_bounds__(256) void wv_mfma_kernel(
  const float* __restrict__ e_attr, const float* __restrict__ rad_w1,
  const _Float16* __restrict__ wh, _Float16* __restrict__ wvg, int BE, int E)
{
  __shared__ _Float16 Hlds[64*HPAD];
  int tid=threadIdx.x, lane=tid&63, wave=tid>>6;
  int e0 = blockIdx.x*64;
  int el = e0 + lane;
  bool active = el < BE;
  float x=0.f,y=0.f,z=0.f;
  if(active){ const float* ea=e_attr+(long)el*3; x=ea[0]; y=ea[1]; z=ea[2]; }
  float rn=sqrtf(x*x+y*y+z*z)+1e-8f;
  #pragma unroll
  for(int j=0;j<8;j++){
    int t = wave*8 + j;
    float a = rn*rad_w1[t];
    Hlds[lane*HPAD + t] = (_Float16)(a/(1.f+expf(-a)));
  }
  __syncthreads();
  f16x8 bf0 = *(const f16x8*)(Hlds + ( 0 + (lane&15))*HPAD + (lane>>4)*8);
  f16x8 bf1 = *(const f16x8*)(Hlds + (16 + (lane&15))*HPAD + (lane>>4)*8);
  f16x8 bf2 = *(const f16x8*)(Hlds + (32 + (lane&15))*HPAD + (lane>>4)*8);
  f16x8 bf3 = *(const f16x8*)(Hlds + (48 + (lane&15))*HPAD + (lane>>4)*8);

  for(int rt=wave; rt<WROWS/16; rt+=4){
    f16x8 af = *(const f16x8*)(wh + (rt*16 + (lane&15))*NHID + (lane>>4)*8);
    f32x4 c0={0.f,0.f,0.f,0.f}, c1=c0, c2=c0, c3=c0;
    c0=__builtin_amdgcn_mfma_f32_16x16x32_f16(af,bf0,c0,0,0,0);
    c1=__builtin_amdgcn_mfma_f32_16x16x32_f16(af,bf1,c1,0,0,0);
    c2=__builtin_amdgcn_mfma_f32_16x16x32_f16(af,bf2,c2,0,0,0);
    c3=__builtin_amdgcn_mfma_f32_16x16x32_f16(af,bf3,c3,0,0,0);
    int rr = rt*16 + 4*(lane>>4);
    int ec = e0 + (lane&15);
    #pragma unroll
    for(int j=0;j<4;j++){
      int row = rr+j;
      if(row < WNUM){
        _Float16* wp = wvg + (size_t)row*BE + ec;
        if(ec    < BE) wp[ 0]=(_Float16)c0[j];
        if(ec+16 < BE) wp[16]=(_Float16)c1[j];
        if(ec+32 < BE) wp[32]=(_Float16)c2[j];
        if(ec+48 < BE) wp[48]=(_Float16)c3[j];
      }
    }
  }
}

// ---------------- Kernel B: one thread per (2 edges, v-unit) — dual-stream ILP ----------------
// Each thread owns edges el_a=base+tid and el_b=base+256+tid (both lane-coalesced).
// Two fully independent Y/M/wv/acc streams double in-flight VMEM per wave.

template<int L1_,int L2_,int L3_,int MUL1,int MULO,int XOFF,int YOFF,int WOFF,int CGOFF>
__device__ __forceinline__ void do_path_v2(
  const float* __restrict__ hsa, const float* __restrict__ hsb,
  const float* Ya, const float* Yb,
  const _Float16* __restrict__ wvg, long ela, long elb, size_t BEs,
  const float* __restrict__ cgl, int v, float* acca, float* accb)
{
  constexpr int N1=2*L1_+1, N2=2*L2_+1, N3=2*L3_+1;
  float Ma[N1*N3], Mb[N1*N3];
  #pragma unroll
  for(int i=0;i<N1;i++){
    #pragma unroll
    for(int k=0;k<N3;k++){
      float sa=0.f, sb=0.f;
      #pragma unroll
      for(int j=0;j<N2;j++){
        float c = cgl[CGOFF+(i*N2+j)*N3+k];
        sa += Ya[YOFF+j]*c;
        sb += Yb[YOFF+j]*c;
      }
      Ma[i*N3+k]=sa; Mb[i*N3+k]=sb;
    }
  }
  #pragma unroll
  for(int u=0;u<MUL1;u++){
    const _Float16* wr = wvg + (size_t)(WOFF+u*MULO+v)*BEs;
    float wa = (float)wr[ela];
    float wb = (float)wr[elb];
    #pragma unroll
    for(int k=0;k<N3;k++){
      float za=0.f, zb=0.f;
      #pragma unroll
      for(int i=0;i<N1;i++){
        za += hsa[XOFF+u*N1+i]*Ma[i*N3+k];
        zb += hsb[XOFF+u*N1+i]*Mb[i*N3+k];
      }
      acca[k] += za*wa;
      accb[k] += zb*wb;
    }
  }
}

__global__ __launch_bounds__(256) void tp_out_kernel(
  const float* __restrict__ h_in, const int* __restrict__ e_src, const int* __restrict__ e_dst,
  const float* __restrict__ e_attr, const _Float16* __restrict__ wvg,
  const float* __restrict__ cg, float* __restrict__ out, int BE, int N, int E)
{
  __shared__ float cgl[640];
  for(int i=threadIdx.x;i<621;i+=256) cgl[i]=cg[i];
  __syncthreads();
  long base = (long)blockIdx.y*512;
  long ela = base + threadIdx.x;
  if(ela>=BE) return;
  long elb = base + 256 + threadIdx.x;
  bool vb = elb < BE;
  long elbc = vb ? elb : ela;          // clamped for safe reads
  int vu = blockIdx.x;                 // 0..25, block-uniform
  size_t BEs = (size_t)BE;

  int ba = (int)(ela / E), bb = (int)(elbc / E);
  int srca = e_src[ela], dsta = e_dst[ela];
  int srcb = e_src[elbc], dstb = e_dst[elbc];
  const float* eaa = e_attr + ela*3;
  const float* eab = e_attr + elbc*3;
  float xa=eaa[0], ya=eaa[1], za_=eaa[2];
  float xb=eab[0], yb=eab[1], zb_=eab[2];
  float rna = sqrtf(xa*xa+ya*ya+za_*za_) + 1e-8f;
  float rnb = sqrtf(xb*xb+yb*yb+zb_*zb_) + 1e-8f;
  float xha=xa/rna, yha=ya/rna, zha=za_/rna;
  float xhb=xb/rnb, yhb=yb/rnb, zhb=zb_/rnb;
  const float s3=1.7320508075688772f, s5=2.23606797749979f, s15=3.872983346207417f;
  float Ya[9], Yb[9];
  Ya[0]=1.f; Ya[1]=s3*yha; Ya[2]=s3*zha; Ya[3]=s3*xha;
  Ya[4]=s15*xha*yha; Ya[5]=s15*yha*zha; Ya[6]=0.5f*s5*(3.f*zha*zha-1.f);
  Ya[7]=s15*xha*zha; Ya[8]=0.5f*s15*(xha*xha-yha*yha);
  Yb[0]=1.f; Yb[1]=s3*yhb; Yb[2]=s3*zhb; Yb[3]=s3*xhb;
  Yb[4]=s15*xhb*yhb; Yb[5]=s15*yhb*zhb; Yb[6]=0.5f*s5*(3.f*zhb*zhb-1.f);
  Yb[7]=s15*xhb*zhb; Yb[8]=0.5f*s15*(xhb*xhb-yhb*yhb);
  const float* hsa = h_in + ((long)ba*N + srca)*DIM;
  const float* hsb = h_in + ((long)bb*N + srcb)*DIM;
  float* opa = out + ((long)ba*N + dsta)*DIM;
  float* opb = out + ((long)bb*N + dstb)*DIM;
  float acca[5], accb[5];
  #pragma unroll
  for(int i=0;i<5;i++){ acca[i]=0.f; accb[i]=0.f; }

  if(vu<12){                                  // group 0: v=vu, N3=1 -> d=v
    int v=vu;
    //          L1 L2 L3 M1 MO  XO YO WOFF CGOFF
    do_path_v2<0,0,0,12,12,  0,0,   0,   0>(hsa,hsb,Ya,Yb,wvg,ela,elbc,BEs,cgl,v,acca,accb);
    do_path_v2<1,1,0, 4,12, 12,1, 280,  44>(hsa,hsb,Ya,Yb,wvg,ela,elbc,BEs,cgl,v,acca,accb);
    do_path_v2<2,2,0, 6,12, 36,4, 516, 396>(hsa,hsb,Ya,Yb,wvg,ela,elbc,BEs,cgl,v,acca,accb);
    const float a0=0.21320071635561044f;      // sqrt(1/22)
    unsafeAtomicAdd(&opa[v], acca[0]*a0);
    if(vb) unsafeAtomicAdd(&opb[v], accb[0]*a0);
  } else if(vu<16){                           // group 1: v=vu-12, N3=3 -> d=12+v*3+k
    int v=vu-12;
    do_path_v2<0,1,1,12, 4,  0,1, 144,   1>(hsa,hsb,Ya,Yb,wvg,ela,elbc,BEs,cgl,v,acca,accb);
    do_path_v2<1,0,1, 4, 4, 12,0, 264,  35>(hsa,hsb,Ya,Yb,wvg,ela,elbc,BEs,cgl,v,acca,accb);
    do_path_v2<1,2,1, 4, 4, 12,4, 368, 125>(hsa,hsb,Ya,Yb,wvg,ela,elbc,BEs,cgl,v,acca,accb);
    do_path_v2<1,1,1, 4, 4, 24,1, 400, 179>(hsa,hsb,Ya,Yb,wvg,ela,elbc,BEs,cgl,v,acca,accb);
    do_path_v2<2,1,1, 6, 4, 36,1, 492, 351>(hsa,hsb,Ya,Yb,wvg,ela,elbc,BEs,cgl,v,acca,accb);
    const float a1=0.31622776601683794f;      // sqrt(3/30)
    #pragma unroll
    for(int k=0;k<3;k++){
      unsafeAtomicAdd(&opa[12+v*3+k], acca[k]*a1);
      if(vb) unsafeAtomicAdd(&opb[12+v*3+k], accb[k]*a1);
    }
  } else if(vu<20){                           // group 2: v=vu-16, N3=3 -> d=24+v*3+k
    int v=vu-16;
    do_path_v2<1,1,1, 4, 4, 12,1, 328,  53>(hsa,hsb,Ya,Yb,wvg,ela,elbc,BEs,cgl,v,acca,accb);
    do_path_v2<1,0,1, 4, 4, 24,0, 384, 170>(hsa,hsb,Ya,Yb,wvg,ela,elbc,BEs,cgl,v,acca,accb);
    do_path_v2<1,2,1, 4, 4, 24,4, 416, 206>(hsa,hsb,Ya,Yb,wvg,ela,elbc,BEs,cgl,v,acca,accb);
    do_path_v2<2,2,1, 6, 4, 36,4, 588, 421>(hsa,hsb,Ya,Yb,wvg,ela,elbc,BEs,cgl,v,acca,accb);
    const float a2=0.4082482904638631f;       // sqrt(3/18)
    #pragma unroll
    for(int k=0;k<3;k++){
      unsafeAtomicAdd(&opa[24+v*3+k], acca[k]*a2);
      if(vb) unsafeAtomicAdd(&opb[24+v*3+k], accb[k]*a2);
    }
  } else {                                    // group 3: v=vu-20, N3=5 -> d=36+v*5+k
    int v=vu-20;
    do_path_v2<0,2,2,12, 6,  0,4, 192,  10>(hsa,hsb,Ya,Yb,wvg,ela,elbc,BEs,cgl,v,acca,accb);
    do_path_v2<1,1,2, 4, 6, 12,1, 344,  80>(hsa,hsb,Ya,Yb,wvg,ela,elbc,BEs,cgl,v,acca,accb);
    do_path_v2<1,2,2, 4, 6, 24,4, 432, 251>(hsa,hsb,Ya,Yb,wvg,ela,elbc,BEs,cgl,v,acca,accb);
    do_path_v2<2,0,2, 6, 6, 36,0, 456, 326>(hsa,hsb,Ya,Yb,wvg,ela,elbc,BEs,cgl,v,acca,accb);
    do_path_v2<2,2,2, 6, 6, 36,4, 612, 496>(hsa,hsb,Ya,Yb,wvg,ela,elbc,BEs,cgl,v,acca,accb);
    const float a3=0.3952847075210474f;       // sqrt(5/32)
    #pragma unroll
    for(int k=0;k<5;k++){
      unsafeAtomicAdd(&opa[36+v*5+k], acca[k]*a3);
      if(vb) unsafeAtomicAdd(&opb[36+v*5+k], accb[k]*a3);
    }
  }
}

// ---------------- norm_act (in place on d_out) ----------------

__global__ void norm_act_kernel(float* __restrict__ out, int total){
  int idx=blockIdx.x*blockDim.x+threadIdx.x;
  if(idx>=total) return;
  int c = idx % 26; long bn = idx / 26;
  int off, len;
  if(c<12){ off=c; len=1; }
  else if(c<16){ off=12+(c-12)*3; len=3; }
  else if(c<20){ off=24+(c-16)*3; len=3; }
  else { off=36+(c-20)*5; len=5; }
  float* p = out + bn*(long)DIM + off;
  float sum=0.f;
  for(int i=0;i<len;i++){ float v=p[i]; sum+=v*v; }
  float n = sqrtf(sum+1e-12f);
  float sc = 1.f/(1.f+expf(-n));  // silu(n)/n = sigmoid(n)
  for(int i=0;i<len;i++) p[i]*=sc;
}

// ---------------- launch ----------------

extern "C" void kernel_launch(void* const* d_in, const int* in_sizes, int n_in,
                              void* d_out, int out_size, void* d_ws, size_t ws_size,
                              hipStream_t stream)
{
  const float* h       = (const float*)d_in[0];
  const int*   e_src   = (const int*)  d_in[1];
  const int*   e_dst   = (const int*)  d_in[2];
  const float* e_attr  = (const float*)d_in[3];
  const float* lw0     = (const float*)d_in[4];
  const float* lw1o    = (const float*)d_in[5];
  const float* lw1e    = (const float*)d_in[6];
  const float* lw2     = (const float*)d_in[7];
  const float* lb0     = (const float*)d_in[8];
  const float* rw0     = (const float*)d_in[9];
  const float* rw1o    = (const float*)d_in[10];
  const float* rw1e    = (const float*)d_in[11];
  const float* rw2     = (const float*)d_in[12];
  const float* rb0     = (const float*)d_in[13];
  const float* rad_w1  = (const float*)d_in[14];
  const float* rad_w2  = (const float*)d_in[15];

  const int B  = 2;
  const int BE = in_sizes[1];        // B*E
  const int E  = BE / B;
  const int BN = in_sizes[0] / DIM;  // B*N
  const int N  = BN / B;

  float* ws   = (float*)d_ws;
  float* h_in = ws;                                   // BN*DIM floats
  float* cg   = ws + (size_t)BN*DIM;                  // 621 floats (pad to 640)
  _Float16* wh  = (_Float16*)(cg + 640);              // WROWS*NHID halves
  _Float16* wvg = wh + (size_t)WROWS*NHID;            // WNUM*BE halves (~130 MB)

  cg_init_kernel<<<NPATH, 128, 0, stream>>>(cg);
  int whn = WROWS*NHID;
  wh_pack_kernel<<<(whn+255)/256, 256, 0, stream>>>(rad_w2, wh);
  int totL = BN*DIM;
  linear_kernel<<<(totL+255)/256, 256, 0, stream>>>(h, lw0, lw1o, lw1e, lw2, lb0,
                                                    rw0, rw1o, rw1e, rw2, rb0,
                                                    h_in, (float*)d_out, totL);
  int ablk = (BE+63)/64;
  wv_mfma_kernel<<<ablk, 256, 0, stream>>>(e_attr, rad_w1, wh, wvg, BE, E);
  dim3 bgrid(26, (BE+511)/512);
  tp_out_kernel<<<bgrid, 256, 0, stream>>>(h_in, e_src, e_dst, e_attr,
                                           wvg, cg, (float*)d_out, BE, N, E);
  int totN = BN*26;
  norm_act_kernel<<<(totN+255)/256, 256, 0, stream>>>((float*)d_out, totN);
}

// Round 24
// 423.268 us; speedup vs baseline: 1.2432x; 1.2432x over previous
//
#include <hip/hip_runtime.h>
#include <math.h>

#define DIM 66
#define NPATH 17
#define WNUM 648
#define NHID 32
#define HPAD 40
#define WROWS 656

typedef _Float16 f16x8 __attribute__((ext_vector_type(8)));
typedef float f32x4 __attribute__((ext_vector_type(4)));

// ---------------- CG computation (device, mirrors reference exactly) ----------------

__device__ double dfact(int n){ double f=1.0; for(int i=2;i<=n;i++) f*=(double)i; return f; }

__device__ double su2_cg(int j1,int j2,int j3,int m1,int m2,int m3){
  if(m1+m2!=m3) return 0.0;
  double pre = sqrt((double)(2*j3+1)*dfact(j3+j1-j2)*dfact(j3-j1+j2)*dfact(j1+j2-j3)/dfact(j1+j2+j3+1));
  pre *= sqrt(dfact(j3+m3)*dfact(j3-m3)*dfact(j1-m1)*dfact(j1+m1)*dfact(j2-m2)*dfact(j2+m2));
  double s=0.0;
  for(int k=0;k<=j1+j2-j3;k++){
    int a0=k, a1=j1+j2-j3-k, a2=j1-m1-k, a3=j2+m2-k, a4=j3-j2+m1+k, a5=j3-j1-m2+k;
    if(a0<0||a1<0||a2<0||a3<0||a4<0||a5<0) continue;
    double d = dfact(a0)*dfact(a1)*dfact(a2)*dfact(a3)*dfact(a4)*dfact(a5);
    s += ((k&1)? -1.0:1.0)/d;
  }
  return pre*s;
}

__device__ void u_real_entry(int l, int row, int col, double& re, double& im){
  re=0.0; im=0.0;
  const double sq = 0.7071067811865476;
  int m = row - l;
  if(m>0){
    if(col==l+m) re = ((m&1)? -sq : sq);
    else if(col==l-m) re = sq;
  } else if(m==0){
    if(col==l) re = 1.0;
  } else {
    int am = -m;
    if(col==l+m) im = sq;
    else if(col==l-m) im = ((am&1)? sq : -sq);
  }
}

__constant__ int c_l1[NPATH]   = {0,0,0,1,1,1,1,1,1,1,1,1,2,2,2,2,2};
__constant__ int c_l2[NPATH]   = {0,1,2,0,1,1,1,2,0,1,2,2,0,1,2,2,2};
__constant__ int c_l3[NPATH]   = {0,1,2,1,0,1,2,1,1,1,1,2,2,1,0,1,2};
__constant__ int c_cgoff[NPATH]= {0,1,10,35,44,53,80,125,170,179,206,251,326,351,396,421,496};

__global__ void cg_init_kernel(float* __restrict__ cg_out){
  int p = blockIdx.x;
  int l1=c_l1[p], l2=c_l2[p], l3=c_l3[p];
  int n1=2*l1+1, n2=2*l2+1, n3=2*l3+1;
  int ntot=n1*n2*n3;
  __shared__ double Cc[125];
  __shared__ double red[128];
  int t=threadIdx.x;
  if(t<ntot){
    int i=t/(n2*n3), j=(t/n3)%n2, k=t%n3;
    Cc[t] = su2_cg(l1,l2,l3,i-l1,j-l2,k-l3);
  }
  __syncthreads();
  double Tre=0.0, Tim=0.0;
  if(t<ntot){
    int a=t/(n2*n3), b=(t/n3)%n2, c=t%n3;
    for(int i=0;i<n1;i++)for(int j=0;j<n2;j++)for(int k=0;k<n3;k++){
      double cc=Cc[(i*n2+j)*n3+k];
      if(cc==0.0) continue;
      double u1r,u1i,u2r,u2i,u3r,u3i;
      u_real_entry(l1,a,i,u1r,u1i); u1i=-u1i;
      u_real_entry(l2,b,j,u2r,u2i); u2i=-u2i;
      u_real_entry(l3,c,k,u3r,u3i);
      double pr=u1r*u2r-u1i*u2i, pi=u1r*u2i+u1i*u2r;
      double qr=pr*u3r-pi*u3i,   qi=pr*u3i+pi*u3r;
      Tre+=qr*cc; Tim+=qi*cc;
    }
  }
  red[t]=fabs(Tre); __syncthreads();
  for(int s=64;s>0;s>>=1){ if(t<s) red[t]+=red[t+s]; __syncthreads(); }
  double sar=red[0]; __syncthreads();
  red[t]=fabs(Tim); __syncthreads();
  for(int s=64;s>0;s>>=1){ if(t<s) red[t]+=red[t+s]; __syncthreads(); }
  double sai=red[0]; __syncthreads();
  double chosen = (sar>=sai)? Tre : Tim;
  red[t]=chosen*chosen; __syncthreads();
  for(int s=64;s>0;s>>=1){ if(t<s) red[t]+=red[t+s]; __syncthreads(); }
  double nrm=sqrt(red[0]);
  if(t<ntot) cg_out[c_cgoff[p]+t] = (float)(chosen/nrm);
}

// ------- W -> f16 -------

__global__ void wh_pack_kernel(const float* __restrict__ w2, _Float16* __restrict__ wh){
  int i=blockIdx.x*blockDim.x+threadIdx.x;
  if(i>=WROWS*NHID) return;
  int nr=i>>5, t=i&31;
  float val = (nr<WNUM) ? w2[t*WNUM+nr]*0.17677669529663687f : 0.f;
  wh[i]=(_Float16)val;
}

// ---------------- per-node linears ----------------

__global__ void linear_kernel(const float* __restrict__ h,
  const float* __restrict__ w0i, const float* __restrict__ w1oi, const float* __restrict__ w1ei,
  const float* __restrict__ w2i, const float* __restrict__ b0i,
  const float* __restrict__ w0r, const float* __restrict__ w1or_, const float* __restrict__ w1er,
  const float* __restrict__ w2r, const float* __restrict__ b0r,
  float* __restrict__ h_in, float* __restrict__ out, int total)
{
  int idx=blockIdx.x*blockDim.x+threadIdx.x;
  if(idx>=total) return;
  int d = idx % DIM;
  long bn = idx / DIM;
  const float* hr = h + bn*(long)DIM;
  float s1=0.f, s2=0.f, o1, o2;
  if(d<12){
    #pragma unroll
    for(int u=0;u<12;u++){ float xv=hr[u]; s1+=xv*w0i[u*12+d]; s2+=xv*w0r[u*12+d]; }
    const float r = 0.28867513459481287f;
    o1 = s1*r + b0i[d]; o2 = s2*r + b0r[d];
  } else if(d<24){
    int rel=d-12, v=rel/3, i=rel%3;
    #pragma unroll
    for(int u=0;u<4;u++){ float xv=hr[12+u*3+i]; s1+=xv*w1oi[u*4+v]; s2+=xv*w1or_[u*4+v]; }
    o1=s1*0.5f; o2=s2*0.5f;
  } else if(d<36){
    int rel=d-24, v=rel/3, i=rel%3;
    #pragma unroll
    for(int u=0;u<4;u++){ float xv=hr[24+u*3+i]; s1+=xv*w1ei[u*4+v]; s2+=xv*w1er[u*4+v]; }
    o1=s1*0.5f; o2=s2*0.5f;
  } else {
    int rel=d-36, v=rel/5, i=rel%5;
    #pragma unroll
    for(int u=0;u<6;u++){ float xv=hr[36+u*5+i]; s1+=xv*w2i[u*6+v]; s2+=xv*w2r[u*6+v]; }
    const float r=0.4082482904638631f;
    o1=s1*r; o2=s2*r;
  }
  h_in[idx]=o1; out[idx]=o2;
}

// ---------------- Kernel A: wv via MFMA (verified R19-R23) ----------------

__global__ __launch_bounds__(256) void wv_mfma_kernel(
  const float* __restrict__ e_attr, const float* __restrict__ rad_w1,
  const _Float16* __restrict__ wh, _Float16* __restrict__ wvg, int BE, int E)
{
  __shared__ _Float16 Hlds[64*HPAD];
  int tid=threadIdx.x, lane=tid&63, wave=tid>>6;
  int e0 = blockIdx.x*64;
  int el = e0 + lane;
  bool active = el < BE;
  float x=0.f,y=0.f,z=0.f;
  if(active){ const float* ea=e_attr+(long)el*3; x=ea[0]; y=ea[1]; z=ea[2]; }
  float rn=sqrtf(x*x+y*y+z*z)+1e-8f;
  #pragma unroll
  for(int j=0;j<8;j++){
    int t = wave*8 + j;
    float a = rn*rad_w1[t];
    Hlds[lane*HPAD + t] = (_Float16)(a/(1.f+expf(-a)));
  }
  __syncthreads();
  f16x8 bf0 = *(const f16x8*)(Hlds + ( 0 + (lane&15))*HPAD + (lane>>4)*8);
  f16x8 bf1 = *(const f16x8*)(Hlds + (16 + (lane&15))*HPAD + (lane>>4)*8);
  f16x8 bf2 = *(const f16x8*)(Hlds + (32 + (lane&15))*HPAD + (lane>>4)*8);
  f16x8 bf3 = *(const f16x8*)(Hlds + (48 + (lane&15))*HPAD + (lane>>4)*8);

  for(int rt=wave; rt<WROWS/16; rt+=4){
    f16x8 af = *(const f16x8*)(wh + (rt*16 + (lane&15))*NHID + (lane>>4)*8);
    f32x4 c0={0.f,0.f,0.f,0.f}, c1=c0, c2=c0, c3=c0;
    c0=__builtin_amdgcn_mfma_f32_16x16x32_f16(af,bf0,c0,0,0,0);
    c1=__builtin_amdgcn_mfma_f32_16x16x32_f16(af,bf1,c1,0,0,0);
    c2=__builtin_amdgcn_mfma_f32_16x16x32_f16(af,bf2,c2,0,0,0);
    c3=__builtin_amdgcn_mfma_f32_16x16x32_f16(af,bf3,c3,0,0,0);
    int rr = rt*16 + 4*(lane>>4);
    int ec = e0 + (lane&15);
    #pragma unroll
    for(int j=0;j<4;j++){
      int row = rr+j;
      if(row < WNUM){
        _Float16* wp = wvg + (size_t)row*BE + ec;
        if(ec    < BE) wp[ 0]=(_Float16)c0[j];
        if(ec+16 < BE) wp[16]=(_Float16)c1[j];
        if(ec+32 < BE) wp[32]=(_Float16)c2[j];
        if(ec+48 < BE) wp[48]=(_Float16)c3[j];
      }
    }
  }
}

// ---------------- CSR build ----------------

__global__ void zero_int_kernel(int* __restrict__ p, int n){
  int i=blockIdx.x*blockDim.x+threadIdx.x;
  if(i<n) p[i]=0;
}

__global__ void count_kernel(const int* __restrict__ e_dst, int* __restrict__ cnt, int BE, int N, int E){
  int el=blockIdx.x*blockDim.x+threadIdx.x;
  if(el>=BE) return;
  int b=el/E;
  atomicAdd(&cnt[b*N+e_dst[el]], 1);
}

__global__ void scan_kernel(const int* __restrict__ cnt, int* __restrict__ off, int BN){
  __shared__ int part[1024];
  int t=threadIdx.x;
  int items=(BN+1023)>>10;
  int base=t*items;
  int s=0;
  for(int i=0;i<items;i++){ int idx=base+i; if(idx<BN) s+=cnt[idx]; }
  part[t]=s; __syncthreads();
  for(int d=1;d<1024;d<<=1){
    int v=(t>=d)?part[t-d]:0; __syncthreads();
    part[t]+=v; __syncthreads();
  }
  int run=(t==0)?0:part[t-1];
  for(int i=0;i<items;i++){ int idx=base+i; if(idx<BN){ off[idx]=run; run+=cnt[idx]; } }
}

__global__ void fill_kernel(const int* __restrict__ e_dst, const int* __restrict__ off,
                            int* __restrict__ cursor, int* __restrict__ elist, int BE, int N, int E){
  int el=blockIdx.x*blockDim.x+threadIdx.x;
  if(el>=BE) return;
  int b=el/E;
  int fd=b*N+e_dst[el];
  int pos=atomicAdd(&cursor[fd],1);
  elist[off[fd]+pos]=el;
}

// ---------------- Kernel B: TP per (edge, v-unit); atomic or msg-store ----------------

template<int L1_,int L2_,int L3_,int MUL1,int MULO,int XOFF,int YOFF,int WOFF,int CGOFF>
__device__ __forceinline__ void do_path_v(const float* __restrict__ hs, const float* Y,
  const _Float16* __restrict__ wvg, long el, size_t BEs, const float* __restrict__ cgl,
  int v, float* acc)
{
  constexpr int N1=2*L1_+1, N2=2*L2_+1, N3=2*L3_+1;
  float M[N1*N3];
  #pragma unroll
  for(int i=0;i<N1;i++){
    #pragma unroll
    for(int k=0;k<N3;k++){
      float s=0.f;
      #pragma unroll
      for(int j=0;j<N2;j++) s += Y[YOFF+j]*cgl[CGOFF+(i*N2+j)*N3+k];
      M[i*N3+k]=s;
    }
  }
  #pragma unroll
  for(int u=0;u<MUL1;u++){
    float w = (float)wvg[(size_t)(WOFF+u*MULO+v)*BEs + el];
    #pragma unroll
    for(int k=0;k<N3;k++){
      float z=0.f;
      #pragma unroll
      for(int i=0;i<N1;i++) z += hs[XOFF+u*N1+i]*M[i*N3+k];
      acc[k] += z*w;
    }
  }
}

template<bool USE_ATOMIC>
__global__ __launch_bounds__(256) void tp_out_kernel(
  const float* __restrict__ h_in, const int* __restrict__ e_src, const int* __restrict__ e_dst,
  const float* __restrict__ e_attr, const _Float16* __restrict__ wvg,
  const float* __restrict__ cg, float* __restrict__ outdst, int BE, int N, int E)
{
  // outdst = d_out (atomic path) or msg[d][BE] (store path)
  __shared__ float cgl[640];
  for(int i=threadIdx.x;i<621;i+=256) cgl[i]=cg[i];
  __syncthreads();
  long el = (long)blockIdx.y*256 + threadIdx.x;
  if(el>=BE) return;
  int vu = blockIdx.x;
  size_t BEs = (size_t)BE;
  int b = (int)(el / E);
  int src = e_src[el];
  const float* ea = e_attr + el*3;
  float x=ea[0], y=ea[1], z=ea[2];
  float rn = sqrtf(x*x+y*y+z*z) + 1e-8f;
  float xh=x/rn, yh=y/rn, zh=z/rn;
  float Y[9];
  const float s3=1.7320508075688772f, s5=2.23606797749979f, s15=3.872983346207417f;
  Y[0]=1.f; Y[1]=s3*yh; Y[2]=s3*zh; Y[3]=s3*xh;
  Y[4]=s15*xh*yh; Y[5]=s15*yh*zh; Y[6]=0.5f*s5*(3.f*zh*zh-1.f);
  Y[7]=s15*xh*zh; Y[8]=0.5f*s15*(xh*xh-yh*yh);
  const float* hs = h_in + ((long)b*N + src)*DIM;
  float* op = USE_ATOMIC ? (outdst + ((long)b*N + e_dst[el])*DIM) : nullptr;
  float acc[5];
  #pragma unroll
  for(int i=0;i<5;i++) acc[i]=0.f;

  if(vu<12){
    int v=vu;
    do_path_v<0,0,0,12,12,  0,0,   0,   0>(hs,Y,wvg,el,BEs,cgl,v,acc);
    do_path_v<1,1,0, 4,12, 12,1, 280,  44>(hs,Y,wvg,el,BEs,cgl,v,acc);
    do_path_v<2,2,0, 6,12, 36,4, 516, 396>(hs,Y,wvg,el,BEs,cgl,v,acc);
    float r = acc[0]*0.21320071635561044f;
    if(USE_ATOMIC) unsafeAtomicAdd(&op[v], r);
    else outdst[(size_t)v*BEs + el] = r;
  } else if(vu<16){
    int v=vu-12;
    do_path_v<0,1,1,12, 4,  0,1, 144,   1>(hs,Y,wvg,el,BEs,cgl,v,acc);
    do_path_v<1,0,1, 4, 4, 12,0, 264,  35>(hs,Y,wvg,el,BEs,cgl,v,acc);
    do_path_v<1,2,1, 4, 4, 12,4, 368, 125>(hs,Y,wvg,el,BEs,cgl,v,acc);
    do_path_v<1,1,1, 4, 4, 24,1, 400, 179>(hs,Y,wvg,el,BEs,cgl,v,acc);
    do_path_v<2,1,1, 6, 4, 36,1, 492, 351>(hs,Y,wvg,el,BEs,cgl,v,acc);
    #pragma unroll
    for(int k=0;k<3;k++){
      float r = acc[k]*0.31622776601683794f;
      int d = 12+v*3+k;
      if(USE_ATOMIC) unsafeAtomicAdd(&op[d], r);
      else outdst[(size_t)d*BEs + el] = r;
    }
  } else if(vu<20){
    int v=vu-16;
    do_path_v<1,1,1, 4, 4, 12,1, 328,  53>(hs,Y,wvg,el,BEs,cgl,v,acc);
    do_path_v<1,0,1, 4, 4, 24,0, 384, 170>(hs,Y,wvg,el,BEs,cgl,v,acc);
    do_path_v<1,2,1, 4, 4, 24,4, 416, 206>(hs,Y,wvg,el,BEs,cgl,v,acc);
    do_path_v<2,2,1, 6, 4, 36,4, 588, 421>(hs,Y,wvg,el,BEs,cgl,v,acc);
    #pragma unroll
    for(int k=0;k<3;k++){
      float r = acc[k]*0.4082482904638631f;
      int d = 24+v*3+k;
      if(USE_ATOMIC) unsafeAtomicAdd(&op[d], r);
      else outdst[(size_t)d*BEs + el] = r;
    }
  } else {
    int v=vu-20;
    do_path_v<0,2,2,12, 6,  0,4, 192,  10>(hs,Y,wvg,el,BEs,cgl,v,acc);
    do_path_v<1,1,2, 4, 6, 12,1, 344,  80>(hs,Y,wvg,el,BEs,cgl,v,acc);
    do_path_v<1,2,2, 4, 6, 24,4, 432, 251>(hs,Y,wvg,el,BEs,cgl,v,acc);
    do_path_v<2,0,2, 6, 6, 36,0, 456, 326>(hs,Y,wvg,el,BEs,cgl,v,acc);
    do_path_v<2,2,2, 6, 6, 36,4, 612, 496>(hs,Y,wvg,el,BEs,cgl,v,acc);
    #pragma unroll
    for(int k=0;k<5;k++){
      float r = acc[k]*0.3952847075210474f;
      int d = 36+v*5+k;
      if(USE_ATOMIC) unsafeAtomicAdd(&op[d], r);
      else outdst[(size_t)d*BEs + el] = r;
    }
  }
}

// ---------------- gather: one thread per (node,d); single writer ----------------

__global__ __launch_bounds__(256) void gather_kernel(
  const float* __restrict__ msg, const int* __restrict__ cnt, const int* __restrict__ off,
  const int* __restrict__ elist, float* __restrict__ out, int BN, int BE)
{
  long node = (long)blockIdx.y*256 + threadIdx.x;
  if(node>=BN) return;
  int d = blockIdx.x;
  int c = cnt[node], o = off[node];
  const float* mrow = msg + (size_t)d*BE;
  float s=0.f;
  for(int i=0;i<c;i++) s += mrow[elist[o+i]];
  out[node*DIM + d] += s;
}

// ---------------- norm_act ----------------

__global__ void norm_act_kernel(float* __restrict__ out, int total){
  int idx=blockIdx.x*blockDim.x+threadIdx.x;
  if(idx>=total) return;
  int c = idx % 26; long bn = idx / 26;
  int off, len;
  if(c<12){ off=c; len=1; }
  else if(c<16){ off=12+(c-12)*3; len=3; }
  else if(c<20){ off=24+(c-16)*3; len=3; }
  else { off=36+(c-20)*5; len=5; }
  float* p = out + bn*(long)DIM + off;
  float sum=0.f;
  for(int i=0;i<len;i++){ float v=p[i]; sum+=v*v; }
  float n = sqrtf(sum+1e-12f);
  float sc = 1.f/(1.f+expf(-n));
  for(int i=0;i<len;i++) p[i]*=sc;
}

// ---------------- launch ----------------

extern "C" void kernel_launch(void* const* d_in, const int* in_sizes, int n_in,
                              void* d_out, int out_size, void* d_ws, size_t ws_size,
                              hipStream_t stream)
{
  const float* h       = (const float*)d_in[0];
  const int*   e_src   = (const int*)  d_in[1];
  const int*   e_dst   = (const int*)  d_in[2];
  const float* e_attr  = (const float*)d_in[3];
  const float* lw0     = (const float*)d_in[4];
  const float* lw1o    = (const float*)d_in[5];
  const float* lw1e    = (const float*)d_in[6];
  const float* lw2     = (const float*)d_in[7];
  const float* lb0     = (const float*)d_in[8];
  const float* rw0     = (const float*)d_in[9];
  const float* rw1o    = (const float*)d_in[10];
  const float* rw1e    = (const float*)d_in[11];
  const float* rw2     = (const float*)d_in[12];
  const float* rb0     = (const float*)d_in[13];
  const float* rad_w1  = (const float*)d_in[14];
  const float* rad_w2  = (const float*)d_in[15];

  const int B  = 2;
  const int BE = in_sizes[1];
  const int E  = BE / B;
  const int BN = in_sizes[0] / DIM;
  const int N  = BN / B;

  float* ws   = (float*)d_ws;
  float* h_in = ws;
  float* cg   = ws + (size_t)BN*DIM;
  _Float16* wh  = (_Float16*)(cg + 640);
  _Float16* wvg = wh + (size_t)WROWS*NHID;
  float* msg  = (float*)(wvg + (size_t)WNUM*BE);          // DIM*BE floats
  int*   cnt  = (int*)(msg + (size_t)DIM*BE);
  int*   offp = cnt + BN;
  int*   cur  = offp + BN;
  int*   elist= cur + BN;

  size_t need_f = (size_t)BN*DIM + 640 + ((size_t)WROWS*NHID)/2
                + ((size_t)WNUM*BE)/2 + (size_t)DIM*BE + 3*(size_t)BN + (size_t)BE;
  bool csr_ok = (ws_size/4) >= need_f + 1024;

  cg_init_kernel<<<NPATH, 128, 0, stream>>>(cg);
  int whn = WROWS*NHID;
  wh_pack_kernel<<<(whn+255)/256, 256, 0, stream>>>(rad_w2, wh);
  int totL = BN*DIM;
  linear_kernel<<<(totL+255)/256, 256, 0, stream>>>(h, lw0, lw1o, lw1e, lw2, lb0,
                                                    rw0, rw1o, rw1e, rw2, rb0,
                                                    h_in, (float*)d_out, totL);
  int ablk = (BE+63)/64;
  wv_mfma_kernel<<<ablk, 256, 0, stream>>>(e_attr, rad_w1, wh, wvg, BE, E);

  if(csr_ok){
    // CSR build (int atomics only, ~200K)
    zero_int_kernel<<<(2*BN+255)/256, 256, 0, stream>>>(cnt, 2*BN);  // cnt + cursor? (cnt,off laid cnt,off,cur: zero cnt and cur separately)
    zero_int_kernel<<<(BN+255)/256, 256, 0, stream>>>(cur, BN);
    count_kernel<<<(BE+255)/256, 256, 0, stream>>>(e_dst, cnt, BE, N, E);
    scan_kernel<<<1, 1024, 0, stream>>>(cnt, offp, BN);
    fill_kernel<<<(BE+255)/256, 256, 0, stream>>>(e_dst, offp, cur, elist, BE, N, E);
    // TP -> msg (no float atomics)
    dim3 bgrid(26, (BE+255)/256);
    tp_out_kernel<false><<<bgrid, 256, 0, stream>>>(h_in, e_src, e_dst, e_attr,
                                                    wvg, cg, msg, BE, N, E);
    // gather -> out
    dim3 ggrid(DIM, (BN+255)/256);
    gather_kernel<<<ggrid, 256, 0, stream>>>(msg, cnt, offp, elist, (float*)d_out, BN, BE);
  } else {
    dim3 bgrid(26, (BE+255)/256);
    tp_out_kernel<true><<<bgrid, 256, 0, stream>>>(h_in, e_src, e_dst, e_attr,
                                                   wvg, cg, (float*)d_out, BE, N, E);
  }
  int totN = BN*26;
  norm_act_kernel<<<(totN+255)/256, 256, 0, stream>>>((float*)d_out, totN);
}

// Round 25
// 412.539 us; speedup vs baseline: 1.2755x; 1.0260x over previous
//
#include <hip/hip_runtime.h>
#include <math.h>

#define DIM 66
#define NPATH 17
#define WNUM 648
#define NHID 32

// ---------------- CG computation (device, mirrors reference exactly) ----------------

__device__ double dfact(int n){ double f=1.0; for(int i=2;i<=n;i++) f*=(double)i; return f; }

__device__ double su2_cg(int j1,int j2,int j3,int m1,int m2,int m3){
  if(m1+m2!=m3) return 0.0;
  double pre = sqrt((double)(2*j3+1)*dfact(j3+j1-j2)*dfact(j3-j1+j2)*dfact(j1+j2-j3)/dfact(j1+j2+j3+1));
  pre *= sqrt(dfact(j3+m3)*dfact(j3-m3)*dfact(j1-m1)*dfact(j1+m1)*dfact(j2-m2)*dfact(j2+m2));
  double s=0.0;
  for(int k=0;k<=j1+j2-j3;k++){
    int a0=k, a1=j1+j2-j3-k, a2=j1-m1-k, a3=j2+m2-k, a4=j3-j2+m1+k, a5=j3-j1-m2+k;
    if(a0<0||a1<0||a2<0||a3<0||a4<0||a5<0) continue;
    double d = dfact(a0)*dfact(a1)*dfact(a2)*dfact(a3)*dfact(a4)*dfact(a5);
    s += ((k&1)? -1.0:1.0)/d;
  }
  return pre*s;
}

__device__ void u_real_entry(int l, int row, int col, double& re, double& im){
  re=0.0; im=0.0;
  const double sq = 0.7071067811865476;
  int m = row - l;
  if(m>0){
    if(col==l+m) re = ((m&1)? -sq : sq);
    else if(col==l-m) re = sq;
  } else if(m==0){
    if(col==l) re = 1.0;
  } else {
    int am = -m;
    if(col==l+m) im = sq;
    else if(col==l-m) im = ((am&1)? sq : -sq);
  }
}

__constant__ int c_l1[NPATH]   = {0,0,0,1,1,1,1,1,1,1,1,1,2,2,2,2,2};
__constant__ int c_l2[NPATH]   = {0,1,2,0,1,1,1,2,0,1,2,2,0,1,2,2,2};
__constant__ int c_l3[NPATH]   = {0,1,2,1,0,1,2,1,1,1,1,2,2,1,0,1,2};
__constant__ int c_cgoff[NPATH]= {0,1,10,35,44,53,80,125,170,179,206,251,326,351,396,421,496};

__global__ void cg_init_kernel(float* __restrict__ cg_out){
  int p = blockIdx.x;
  int l1=c_l1[p], l2=c_l2[p], l3=c_l3[p];
  int n1=2*l1+1, n2=2*l2+1, n3=2*l3+1;
  int ntot=n1*n2*n3;
  __shared__ double Cc[125];
  __shared__ double red[128];
  int t=threadIdx.x;
  if(t<ntot){
    int i=t/(n2*n3), j=(t/n3)%n2, k=t%n3;
    Cc[t] = su2_cg(l1,l2,l3,i-l1,j-l2,k-l3);
  }
  __syncthreads();
  double Tre=0.0, Tim=0.0;
  if(t<ntot){
    int a=t/(n2*n3), b=(t/n3)%n2, c=t%n3;
    for(int i=0;i<n1;i++)for(int j=0;j<n2;j++)for(int k=0;k<n3;k++){
      double cc=Cc[(i*n2+j)*n3+k];
      if(cc==0.0) continue;
      double u1r,u1i,u2r,u2i,u3r,u3i;
      u_real_entry(l1,a,i,u1r,u1i); u1i=-u1i;
      u_real_entry(l2,b,j,u2r,u2i); u2i=-u2i;
      u_real_entry(l3,c,k,u3r,u3i);
      double pr=u1r*u2r-u1i*u2i, pi=u1r*u2i+u1i*u2r;
      double qr=pr*u3r-pi*u3i,   qi=pr*u3i+pi*u3r;
      Tre+=qr*cc; Tim+=qi*cc;
    }
  }
  red[t]=fabs(Tre); __syncthreads();
  for(int s=64;s>0;s>>=1){ if(t<s) red[t]+=red[t+s]; __syncthreads(); }
  double sar=red[0]; __syncthreads();
  red[t]=fabs(Tim); __syncthreads();
  for(int s=64;s>0;s>>=1){ if(t<s) red[t]+=red[t+s]; __syncthreads(); }
  double sai=red[0]; __syncthreads();
  double chosen = (sar>=sai)? Tre : Tim;
  red[t]=chosen*chosen; __syncthreads();
  for(int s=64;s>0;s>>=1){ if(t<s) red[t]+=red[t+s]; __syncthreads(); }
  double nrm=sqrt(red[0]);
  if(t<ntot) cg_out[c_cgoff[p]+t] = (float)(chosen/nrm);
}

// ------- W -> f32 row-major [648][32], fold 1/sqrt(32) -------

__global__ void wf_pack_kernel(const float* __restrict__ w2, float* __restrict__ wf){
  int i=blockIdx.x*blockDim.x+threadIdx.x;
  if(i>=WNUM*NHID) return;
  int nr=i>>5, t=i&31;
  wf[i] = w2[t*WNUM+nr]*0.17677669529663687f;
}

// ------- hid[t][el] = silu(rn*rad_w1[t]) -------

__global__ void hid_kernel(const float* __restrict__ e_attr, const float* __restrict__ rad_w1,
                           float* __restrict__ hidg, int BE){
  int el = blockIdx.x*blockDim.x+threadIdx.x;
  if(el>=BE) return;
  int t = blockIdx.y;
  const float* ea = e_attr + (long)el*3;
  float x=ea[0], y=ea[1], z=ea[2];
  float rn = sqrtf(x*x+y*y+z*z)+1e-8f;
  float a = rn*rad_w1[t];
  hidg[(size_t)t*BE + el] = a/(1.f+expf(-a));
}

// ---------------- per-node linears ----------------

__global__ void linear_kernel(const float* __restrict__ h,
  const float* __restrict__ w0i, const float* __restrict__ w1oi, const float* __restrict__ w1ei,
  const float* __restrict__ w2i, const float* __restrict__ b0i,
  const float* __restrict__ w0r, const float* __restrict__ w1or_, const float* __restrict__ w1er,
  const float* __restrict__ w2r, const float* __restrict__ b0r,
  float* __restrict__ h_in, float* __restrict__ out, int total)
{
  int idx=blockIdx.x*blockDim.x+threadIdx.x;
  if(idx>=total) return;
  int d = idx % DIM;
  long bn = idx / DIM;
  const float* hr = h + bn*(long)DIM;
  float s1=0.f, s2=0.f, o1, o2;
  if(d<12){
    #pragma unroll
    for(int u=0;u<12;u++){ float xv=hr[u]; s1+=xv*w0i[u*12+d]; s2+=xv*w0r[u*12+d]; }
    const float r = 0.28867513459481287f;
    o1 = s1*r + b0i[d]; o2 = s2*r + b0r[d];
  } else if(d<24){
    int rel=d-12, v=rel/3, i=rel%3;
    #pragma unroll
    for(int u=0;u<4;u++){ float xv=hr[12+u*3+i]; s1+=xv*w1oi[u*4+v]; s2+=xv*w1or_[u*4+v]; }
    o1=s1*0.5f; o2=s2*0.5f;
  } else if(d<36){
    int rel=d-24, v=rel/3, i=rel%3;
    #pragma unroll
    for(int u=0;u<4;u++){ float xv=hr[24+u*3+i]; s1+=xv*w1ei[u*4+v]; s2+=xv*w1er[u*4+v]; }
    o1=s1*0.5f; o2=s2*0.5f;
  } else {
    int rel=d-36, v=rel/5, i=rel%5;
    #pragma unroll
    for(int u=0;u<6;u++){ float xv=hr[36+u*5+i]; s1+=xv*w2i[u*6+v]; s2+=xv*w2r[u*6+v]; }
    const float r=0.4082482904638631f;
    o1=s1*r; o2=s2*r;
  }
  h_in[idx]=o1; out[idx]=o2;
}

// ---------------- CSR build ----------------

__global__ void zero_int_kernel(int* __restrict__ p, int n){
  int i=blockIdx.x*blockDim.x+threadIdx.x;
  if(i<n) p[i]=0;
}

__global__ void count_kernel(const int* __restrict__ e_dst, int* __restrict__ cnt, int BE, int N, int E){
  int el=blockIdx.x*blockDim.x+threadIdx.x;
  if(el>=BE) return;
  int b=el/E;
  atomicAdd(&cnt[b*N+e_dst[el]], 1);
}

__global__ void scan_kernel(const int* __restrict__ cnt, int* __restrict__ off, int BN){
  __shared__ int part[1024];
  int t=threadIdx.x;
  int items=(BN+1023)>>10;
  int base=t*items;
  int s=0;
  for(int i=0;i<items;i++){ int idx=base+i; if(idx<BN) s+=cnt[idx]; }
  part[t]=s; __syncthreads();
  for(int d=1;d<1024;d<<=1){
    int v=(t>=d)?part[t-d]:0; __syncthreads();
    part[t]+=v; __syncthreads();
  }
  int run=(t==0)?0:part[t-1];
  for(int i=0;i<items;i++){ int idx=base+i; if(idx<BN){ off[idx]=run; run+=cnt[idx]; } }
}

__global__ void fill_kernel(const int* __restrict__ e_dst, const int* __restrict__ off,
                            int* __restrict__ cursor, int* __restrict__ elist, int BE, int N, int E){
  int el=blockIdx.x*blockDim.x+threadIdx.x;
  if(el>=BE) return;
  int b=el/E;
  int fd=b*N+e_dst[el];
  int pos=atomicAdd(&cursor[fd],1);
  elist[off[fd]+pos]=el;
}

// ---------------- Kernel B: fused TP per (edge, v-unit); wv dot computed in-thread ----------------
// w = dot32(W[row] (block-uniform, L1-broadcast), hid[32] (regs, loaded coalesced from L2-resident hidg)).

template<int L1_,int L2_,int L3_,int MUL1,int MULO,int XOFF,int YOFF,int WOFF,int CGOFF>
__device__ __forceinline__ void do_path_f(const float* __restrict__ hs, const float* Y,
  const float* __restrict__ wf, const float* __restrict__ hid,
  const float* __restrict__ cgl, int v, float* acc)
{
  constexpr int N1=2*L1_+1, N2=2*L2_+1, N3=2*L3_+1;
  float M[N1*N3];
  #pragma unroll
  for(int i=0;i<N1;i++){
    #pragma unroll
    for(int k=0;k<N3;k++){
      float s=0.f;
      #pragma unroll
      for(int j=0;j<N2;j++) s += Y[YOFF+j]*cgl[CGOFF+(i*N2+j)*N3+k];
      M[i*N3+k]=s;
    }
  }
  #pragma unroll
  for(int u=0;u<MUL1;u++){
    const float* wr = wf + (WOFF+u*MULO+v)*NHID;   // block-uniform address
    float w0=0.f, w1=0.f;
    #pragma unroll
    for(int t=0;t<NHID/2;t++){ w0 += wr[2*t]*hid[2*t]; w1 += wr[2*t+1]*hid[2*t+1]; }
    float w = w0+w1;
    #pragma unroll
    for(int k=0;k<N3;k++){
      float z=0.f;
      #pragma unroll
      for(int i=0;i<N1;i++) z += hs[XOFF+u*N1+i]*M[i*N3+k];
      acc[k] += z*w;
    }
  }
}

template<bool USE_ATOMIC>
__global__ __launch_bounds__(256) void tp_out_kernel(
  const float* __restrict__ h_in, const int* __restrict__ e_src, const int* __restrict__ e_dst,
  const float* __restrict__ e_attr, const float* __restrict__ hidg, const float* __restrict__ wf,
  const float* __restrict__ cg, float* __restrict__ outdst, int BE, int N, int E)
{
  __shared__ float cgl[640];
  for(int i=threadIdx.x;i<621;i+=256) cgl[i]=cg[i];
  __syncthreads();
  long el = (long)blockIdx.y*256 + threadIdx.x;
  if(el>=BE) return;
  int vu = blockIdx.x;
  size_t BEs = (size_t)BE;
  int b = (int)(el / E);
  int src = e_src[el];
  const float* ea = e_attr + el*3;
  float x=ea[0], y=ea[1], z=ea[2];
  float rn = sqrtf(x*x+y*y+z*z) + 1e-8f;
  float xh=x/rn, yh=y/rn, zh=z/rn;
  float Y[9];
  const float s3=1.7320508075688772f, s5=2.23606797749979f, s15=3.872983346207417f;
  Y[0]=1.f; Y[1]=s3*yh; Y[2]=s3*zh; Y[3]=s3*xh;
  Y[4]=s15*xh*yh; Y[5]=s15*yh*zh; Y[6]=0.5f*s5*(3.f*zh*zh-1.f);
  Y[7]=s15*xh*zh; Y[8]=0.5f*s15*(xh*xh-yh*yh);
  float hid[NHID];
  #pragma unroll
  for(int t=0;t<NHID;t++) hid[t] = hidg[(size_t)t*BEs + el];   // coalesced, L2/L3-resident
  const float* hs = h_in + ((long)b*N + src)*DIM;
  float* op = USE_ATOMIC ? (outdst + ((long)b*N + e_dst[el])*DIM) : nullptr;
  float acc[5];
  #pragma unroll
  for(int i=0;i<5;i++) acc[i]=0.f;

  if(vu<12){
    int v=vu;
    do_path_f<0,0,0,12,12,  0,0,   0,   0>(hs,Y,wf,hid,cgl,v,acc);
    do_path_f<1,1,0, 4,12, 12,1, 280,  44>(hs,Y,wf,hid,cgl,v,acc);
    do_path_f<2,2,0, 6,12, 36,4, 516, 396>(hs,Y,wf,hid,cgl,v,acc);
    float r = acc[0]*0.21320071635561044f;
    if(USE_ATOMIC) unsafeAtomicAdd(&op[v], r);
    else outdst[(size_t)v*BEs + el] = r;
  } else if(vu<16){
    int v=vu-12;
    do_path_f<0,1,1,12, 4,  0,1, 144,   1>(hs,Y,wf,hid,cgl,v,acc);
    do_path_f<1,0,1, 4, 4, 12,0, 264,  35>(hs,Y,wf,hid,cgl,v,acc);
    do_path_f<1,2,1, 4, 4, 12,4, 368, 125>(hs,Y,wf,hid,cgl,v,acc);
    do_path_f<1,1,1, 4, 4, 24,1, 400, 179>(hs,Y,wf,hid,cgl,v,acc);
    do_path_f<2,1,1, 6, 4, 36,1, 492, 351>(hs,Y,wf,hid,cgl,v,acc);
    #pragma unroll
    for(int k=0;k<3;k++){
      float r = acc[k]*0.31622776601683794f;
      int d = 12+v*3+k;
      if(USE_ATOMIC) unsafeAtomicAdd(&op[d], r);
      else outdst[(size_t)d*BEs + el] = r;
    }
  } else if(vu<20){
    int v=vu-16;
    do_path_f<1,1,1, 4, 4, 12,1, 328,  53>(hs,Y,wf,hid,cgl,v,acc);
    do_path_f<1,0,1, 4, 4, 24,0, 384, 170>(hs,Y,wf,hid,cgl,v,acc);
    do_path_f<1,2,1, 4, 4, 24,4, 416, 206>(hs,Y,wf,hid,cgl,v,acc);
    do_path_f<2,2,1, 6, 4, 36,4, 588, 421>(hs,Y,wf,hid,cgl,v,acc);
    #pragma unroll
    for(int k=0;k<3;k++){
      float r = acc[k]*0.4082482904638631f;
      int d = 24+v*3+k;
      if(USE_ATOMIC) unsafeAtomicAdd(&op[d], r);
      else outdst[(size_t)d*BEs + el] = r;
    }
  } else {
    int v=vu-20;
    do_path_f<0,2,2,12, 6,  0,4, 192,  10>(hs,Y,wf,hid,cgl,v,acc);
    do_path_f<1,1,2, 4, 6, 12,1, 344,  80>(hs,Y,wf,hid,cgl,v,acc);
    do_path_f<1,2,2, 4, 6, 24,4, 432, 251>(hs,Y,wf,hid,cgl,v,acc);
    do_path_f<2,0,2, 6, 6, 36,0, 456, 326>(hs,Y,wf,hid,cgl,v,acc);
    do_path_f<2,2,2, 6, 6, 36,4, 612, 496>(hs,Y,wf,hid,cgl,v,acc);
    #pragma unroll
    for(int k=0;k<5;k++){
      float r = acc[k]*0.3952847075210474f;
      int d = 36+v*5+k;
      if(USE_ATOMIC) unsafeAtomicAdd(&op[d], r);
      else outdst[(size_t)d*BEs + el] = r;
    }
  }
}

// ---------------- gather: one thread per (node,d); single writer ----------------

__global__ __launch_bounds__(256) void gather_kernel(
  const float* __restrict__ msg, const int* __restrict__ cnt, const int* __restrict__ off,
  const int* __restrict__ elist, float* __restrict__ out, int BN, int BE)
{
  long node = (long)blockIdx.y*256 + threadIdx.x;
  if(node>=BN) return;
  int d = blockIdx.x;
  int c = cnt[node], o = off[node];
  const float* mrow = msg + (size_t)d*BE;
  float s=0.f;
  for(int i=0;i<c;i++) s += mrow[elist[o+i]];
  out[node*DIM + d] += s;
}

// ---------------- norm_act ----------------

__global__ void norm_act_kernel(float* __restrict__ out, int total){
  int idx=blockIdx.x*blockDim.x+threadIdx.x;
  if(idx>=total) return;
  int c = idx % 26; long bn = idx / 26;
  int off, len;
  if(c<12){ off=c; len=1; }
  else if(c<16){ off=12+(c-12)*3; len=3; }
  else if(c<20){ off=24+(c-16)*3; len=3; }
  else { off=36+(c-20)*5; len=5; }
  float* p = out + bn*(long)DIM + off;
  float sum=0.f;
  for(int i=0;i<len;i++){ float v=p[i]; sum+=v*v; }
  float n = sqrtf(sum+1e-12f);
  float sc = 1.f/(1.f+expf(-n));
  for(int i=0;i<len;i++) p[i]*=sc;
}

// ---------------- launch ----------------

extern "C" void kernel_launch(void* const* d_in, const int* in_sizes, int n_in,
                              void* d_out, int out_size, void* d_ws, size_t ws_size,
                              hipStream_t stream)
{
  const float* h       = (const float*)d_in[0];
  const int*   e_src   = (const int*)  d_in[1];
  const int*   e_dst   = (const int*)  d_in[2];
  const float* e_attr  = (const float*)d_in[3];
  const float* lw0     = (const float*)d_in[4];
  const float* lw1o    = (const float*)d_in[5];
  const float* lw1e    = (const float*)d_in[6];
  const float* lw2     = (const float*)d_in[7];
  const float* lb0     = (const float*)d_in[8];
  const float* rw0     = (const float*)d_in[9];
  const float* rw1o    = (const float*)d_in[10];
  const float* rw1e    = (const float*)d_in[11];
  const float* rw2     = (const float*)d_in[12];
  const float* rb0     = (const float*)d_in[13];
  const float* rad_w1  = (const float*)d_in[14];
  const float* rad_w2  = (const float*)d_in[15];

  const int B  = 2;
  const int BE = in_sizes[1];
  const int E  = BE / B;
  const int BN = in_sizes[0] / DIM;
  const int N  = BN / B;

  float* ws   = (float*)d_ws;
  float* h_in = ws;                                   // BN*DIM
  float* cg   = ws + (size_t)BN*DIM;                  // 640
  float* wf   = cg + 640;                             // WNUM*NHID f32
  float* hidg = wf + WNUM*NHID;                       // NHID*BE f32
  float* msg  = hidg + (size_t)NHID*BE;               // DIM*BE f32
  int*   cnt  = (int*)(msg + (size_t)DIM*BE);
  int*   offp = cnt + BN;
  int*   cur  = offp + BN;
  int*   elist= cur + BN;

  size_t need_f = (size_t)BN*DIM + 640 + (size_t)WNUM*NHID
                + (size_t)NHID*BE + (size_t)DIM*BE + 3*(size_t)BN + (size_t)BE;
  bool csr_ok = (ws_size/4) >= need_f + 1024;

  cg_init_kernel<<<NPATH, 128, 0, stream>>>(cg);
  int wfn = WNUM*NHID;
  wf_pack_kernel<<<(wfn+255)/256, 256, 0, stream>>>(rad_w2, wf);
  dim3 hgrid((BE+255)/256, NHID);
  hid_kernel<<<hgrid, 256, 0, stream>>>(e_attr, rad_w1, hidg, BE);
  int totL = BN*DIM;
  linear_kernel<<<(totL+255)/256, 256, 0, stream>>>(h, lw0, lw1o, lw1e, lw2, lb0,
                                                    rw0, rw1o, rw1e, rw2, rb0,
                                                    h_in, (float*)d_out, totL);
  if(csr_ok){
    zero_int_kernel<<<(BN+255)/256, 256, 0, stream>>>(cnt, BN);
    zero_int_kernel<<<(BN+255)/256, 256, 0, stream>>>(cur, BN);
    count_kernel<<<(BE+255)/256, 256, 0, stream>>>(e_dst, cnt, BE, N, E);
    scan_kernel<<<1, 1024, 0, stream>>>(cnt, offp, BN);
    fill_kernel<<<(BE+255)/256, 256, 0, stream>>>(e_dst, offp, cur, elist, BE, N, E);
    dim3 bgrid(26, (BE+255)/256);
    tp_out_kernel<false><<<bgrid, 256, 0, stream>>>(h_in, e_src, e_dst, e_attr,
                                                    hidg, wf, cg, msg, BE, N, E);
    dim3 ggrid(DIM, (BN+255)/256);
    gather_kernel<<<ggrid, 256, 0, stream>>>(msg, cnt, offp, elist, (float*)d_out, BN, BE);
  } else {
    dim3 bgrid(26, (BE+255)/256);
    tp_out_kernel<true><<<bgrid, 256, 0, stream>>>(h_in, e_src, e_dst, e_attr,
                                                   hidg, wf, cg, (float*)d_out, BE, N, E);
  }
  int totN = BN*26;
  norm_act_kernel<<<(totN+255)/256, 256, 0, stream>>>((float*)d_out, totN);
}

// Round 26
// 339.627 us; speedup vs baseline: 1.5493x; 1.2147x over previous
//
#include <hip/hip_runtime.h>
#include <math.h>

#define DIM 66
#define NPATH 17
#define WNUM 648
#define NHID 32

// ---------------- CG computation (device, mirrors reference exactly) ----------------

__device__ double dfact(int n){ double f=1.0; for(int i=2;i<=n;i++) f*=(double)i; return f; }

__device__ double su2_cg(int j1,int j2,int j3,int m1,int m2,int m3){
  if(m1+m2!=m3) return 0.0;
  double pre = sqrt((double)(2*j3+1)*dfact(j3+j1-j2)*dfact(j3-j1+j2)*dfact(j1+j2-j3)/dfact(j1+j2+j3+1));
  pre *= sqrt(dfact(j3+m3)*dfact(j3-m3)*dfact(j1-m1)*dfact(j1+m1)*dfact(j2-m2)*dfact(j2+m2));
  double s=0.0;
  for(int k=0;k<=j1+j2-j3;k++){
    int a0=k, a1=j1+j2-j3-k, a2=j1-m1-k, a3=j2+m2-k, a4=j3-j2+m1+k, a5=j3-j1-m2+k;
    if(a0<0||a1<0||a2<0||a3<0||a4<0||a5<0) continue;
    double d = dfact(a0)*dfact(a1)*dfact(a2)*dfact(a3)*dfact(a4)*dfact(a5);
    s += ((k&1)? -1.0:1.0)/d;
  }
  return pre*s;
}

__device__ void u_real_entry(int l, int row, int col, double& re, double& im){
  re=0.0; im=0.0;
  const double sq = 0.7071067811865476;
  int m = row - l;
  if(m>0){
    if(col==l+m) re = ((m&1)? -sq : sq);
    else if(col==l-m) re = sq;
  } else if(m==0){
    if(col==l) re = 1.0;
  } else {
    int am = -m;
    if(col==l+m) im = sq;
    else if(col==l-m) im = ((am&1)? sq : -sq);
  }
}

__constant__ int c_l1[NPATH]   = {0,0,0,1,1,1,1,1,1,1,1,1,2,2,2,2,2};
__constant__ int c_l2[NPATH]   = {0,1,2,0,1,1,1,2,0,1,2,2,0,1,2,2,2};
__constant__ int c_l3[NPATH]   = {0,1,2,1,0,1,2,1,1,1,1,2,2,1,0,1,2};
__constant__ int c_cgoff[NPATH]= {0,1,10,35,44,53,80,125,170,179,206,251,326,351,396,421,496};

__global__ void cg_init_kernel(float* __restrict__ cg_out){
  int p = blockIdx.x;
  int l1=c_l1[p], l2=c_l2[p], l3=c_l3[p];
  int n1=2*l1+1, n2=2*l2+1, n3=2*l3+1;
  int ntot=n1*n2*n3;
  __shared__ double Cc[125];
  __shared__ double red[128];
  int t=threadIdx.x;
  if(t<ntot){
    int i=t/(n2*n3), j=(t/n3)%n2, k=t%n3;
    Cc[t] = su2_cg(l1,l2,l3,i-l1,j-l2,k-l3);
  }
  __syncthreads();
  double Tre=0.0, Tim=0.0;
  if(t<ntot){
    int a=t/(n2*n3), b=(t/n3)%n2, c=t%n3;
    for(int i=0;i<n1;i++)for(int j=0;j<n2;j++)for(int k=0;k<n3;k++){
      double cc=Cc[(i*n2+j)*n3+k];
      if(cc==0.0) continue;
      double u1r,u1i,u2r,u2i,u3r,u3i;
      u_real_entry(l1,a,i,u1r,u1i); u1i=-u1i;
      u_real_entry(l2,b,j,u2r,u2i); u2i=-u2i;
      u_real_entry(l3,c,k,u3r,u3i);
      double pr=u1r*u2r-u1i*u2i, pi=u1r*u2i+u1i*u2r;
      double qr=pr*u3r-pi*u3i,   qi=pr*u3i+pi*u3r;
      Tre+=qr*cc; Tim+=qi*cc;
    }
  }
  red[t]=fabs(Tre); __syncthreads();
  for(int s=64;s>0;s>>=1){ if(t<s) red[t]+=red[t+s]; __syncthreads(); }
  double sar=red[0]; __syncthreads();
  red[t]=fabs(Tim); __syncthreads();
  for(int s=64;s>0;s>>=1){ if(t<s) red[t]+=red[t+s]; __syncthreads(); }
  double sai=red[0]; __syncthreads();
  double chosen = (sar>=sai)? Tre : Tim;
  red[t]=chosen*chosen; __syncthreads();
  for(int s=64;s>0;s>>=1){ if(t<s) red[t]+=red[t+s]; __syncthreads(); }
  double nrm=sqrt(red[0]);
  if(t<ntot) cg_out[c_cgoff[p]+t] = (float)(chosen/nrm);
}

// ------- W -> f32 row-major [648][32], fold 1/sqrt(32) -------

__global__ void wf_pack_kernel(const float* __restrict__ w2, float* __restrict__ wf){
  int i=blockIdx.x*blockDim.x+threadIdx.x;
  if(i>=WNUM*NHID) return;
  int nr=i>>5, t=i&31;
  wf[i] = w2[t*WNUM+nr]*0.17677669529663687f;
}

// ------- hid[t][el] = silu(rn*rad_w1[t]) -------

__global__ void hid_kernel(const float* __restrict__ e_attr, const float* __restrict__ rad_w1,
                           float* __restrict__ hidg, int BE){
  int el = blockIdx.x*blockDim.x+threadIdx.x;
  if(el>=BE) return;
  int t = blockIdx.y;
  const float* ea = e_attr + (long)el*3;
  float x=ea[0], y=ea[1], z=ea[2];
  float rn = sqrtf(x*x+y*y+z*z)+1e-8f;
  float a = rn*rad_w1[t];
  hidg[(size_t)t*BE + el] = a/(1.f+expf(-a));
}

// ---------------- per-node linears ----------------

__global__ void linear_kernel(const float* __restrict__ h,
  const float* __restrict__ w0i, const float* __restrict__ w1oi, const float* __restrict__ w1ei,
  const float* __restrict__ w2i, const float* __restrict__ b0i,
  const float* __restrict__ w0r, const float* __restrict__ w1or_, const float* __restrict__ w1er,
  const float* __restrict__ w2r, const float* __restrict__ b0r,
  float* __restrict__ h_in, float* __restrict__ out, int total)
{
  int idx=blockIdx.x*blockDim.x+threadIdx.x;
  if(idx>=total) return;
  int d = idx % DIM;
  long bn = idx / DIM;
  const float* hr = h + bn*(long)DIM;
  float s1=0.f, s2=0.f, o1, o2;
  if(d<12){
    #pragma unroll
    for(int u=0;u<12;u++){ float xv=hr[u]; s1+=xv*w0i[u*12+d]; s2+=xv*w0r[u*12+d]; }
    const float r = 0.28867513459481287f;
    o1 = s1*r + b0i[d]; o2 = s2*r + b0r[d];
  } else if(d<24){
    int rel=d-12, v=rel/3, i=rel%3;
    #pragma unroll
    for(int u=0;u<4;u++){ float xv=hr[12+u*3+i]; s1+=xv*w1oi[u*4+v]; s2+=xv*w1or_[u*4+v]; }
    o1=s1*0.5f; o2=s2*0.5f;
  } else if(d<36){
    int rel=d-24, v=rel/3, i=rel%3;
    #pragma unroll
    for(int u=0;u<4;u++){ float xv=hr[24+u*3+i]; s1+=xv*w1ei[u*4+v]; s2+=xv*w1er[u*4+v]; }
    o1=s1*0.5f; o2=s2*0.5f;
  } else {
    int rel=d-36, v=rel/5, i=rel%5;
    #pragma unroll
    for(int u=0;u<6;u++){ float xv=hr[36+u*5+i]; s1+=xv*w2i[u*6+v]; s2+=xv*w2r[u*6+v]; }
    const float r=0.4082482904638631f;
    o1=s1*r; o2=s2*r;
  }
  h_in[idx]=o1; out[idx]=o2;
}

// ---------------- CSR build ----------------

__global__ void zero_int_kernel(int* __restrict__ p, int n){
  int i=blockIdx.x*blockDim.x+threadIdx.x;
  if(i<n) p[i]=0;
}

__global__ void count_kernel(const int* __restrict__ e_dst, int* __restrict__ cnt, int BE, int N, int E){
  int el=blockIdx.x*blockDim.x+threadIdx.x;
  if(el>=BE) return;
  int b=el/E;
  atomicAdd(&cnt[b*N+e_dst[el]], 1);
}

__global__ void scan_kernel(const int* __restrict__ cnt, int* __restrict__ off, int BN){
  __shared__ int part[1024];
  int t=threadIdx.x;
  int items=(BN+1023)>>10;
  int base=t*items;
  int s=0;
  for(int i=0;i<items;i++){ int idx=base+i; if(idx<BN) s+=cnt[idx]; }
  part[t]=s; __syncthreads();
  for(int d=1;d<1024;d<<=1){
    int v=(t>=d)?part[t-d]:0; __syncthreads();
    part[t]+=v; __syncthreads();
  }
  int run=(t==0)?0:part[t-1];
  for(int i=0;i<items;i++){ int idx=base+i; if(idx<BN){ off[idx]=run; run+=cnt[idx]; } }
}

__global__ void fill_kernel(const int* __restrict__ e_dst, const int* __restrict__ off,
                            int* __restrict__ cursor, int* __restrict__ elist, int BE, int N, int E){
  int el=blockIdx.x*blockDim.x+threadIdx.x;
  if(el>=BE) return;
  int b=el/E;
  int fd=b*N+e_dst[el];
  int pos=atomicAdd(&cursor[fd],1);
  elist[off[fd]+pos]=el;
}

// ---------------- Kernel B: fused TP per (edge, v-unit) (verified R25) ----------------

template<int L1_,int L2_,int L3_,int MUL1,int MULO,int XOFF,int YOFF,int WOFF,int CGOFF>
__device__ __forceinline__ void do_path_f(const float* __restrict__ hs, const float* Y,
  const float* __restrict__ wf, const float* __restrict__ hid,
  const float* __restrict__ cgl, int v, float* acc)
{
  constexpr int N1=2*L1_+1, N2=2*L2_+1, N3=2*L3_+1;
  float M[N1*N3];
  #pragma unroll
  for(int i=0;i<N1;i++){
    #pragma unroll
    for(int k=0;k<N3;k++){
      float s=0.f;
      #pragma unroll
      for(int j=0;j<N2;j++) s += Y[YOFF+j]*cgl[CGOFF+(i*N2+j)*N3+k];
      M[i*N3+k]=s;
    }
  }
  #pragma unroll
  for(int u=0;u<MUL1;u++){
    const float* wr = wf + (WOFF+u*MULO+v)*NHID;
    float w0=0.f, w1=0.f;
    #pragma unroll
    for(int t=0;t<NHID/2;t++){ w0 += wr[2*t]*hid[2*t]; w1 += wr[2*t+1]*hid[2*t+1]; }
    float w = w0+w1;
    #pragma unroll
    for(int k=0;k<N3;k++){
      float z=0.f;
      #pragma unroll
      for(int i=0;i<N1;i++) z += hs[XOFF+u*N1+i]*M[i*N3+k];
      acc[k] += z*w;
    }
  }
}

template<bool USE_ATOMIC>
__global__ __launch_bounds__(256) void tp_out_kernel(
  const float* __restrict__ h_in, const int* __restrict__ e_src, const int* __restrict__ e_dst,
  const float* __restrict__ e_attr, const float* __restrict__ hidg, const float* __restrict__ wf,
  const float* __restrict__ cg, float* __restrict__ outdst, int BE, int N, int E)
{
  __shared__ float cgl[640];
  for(int i=threadIdx.x;i<621;i+=256) cgl[i]=cg[i];
  __syncthreads();
  long el = (long)blockIdx.y*256 + threadIdx.x;
  if(el>=BE) return;
  int vu = blockIdx.x;
  size_t BEs = (size_t)BE;
  int b = (int)(el / E);
  int src = e_src[el];
  const float* ea = e_attr + el*3;
  float x=ea[0], y=ea[1], z=ea[2];
  float rn = sqrtf(x*x+y*y+z*z) + 1e-8f;
  float xh=x/rn, yh=y/rn, zh=z/rn;
  float Y[9];
  const float s3=1.7320508075688772f, s5=2.23606797749979f, s15=3.872983346207417f;
  Y[0]=1.f; Y[1]=s3*yh; Y[2]=s3*zh; Y[3]=s3*xh;
  Y[4]=s15*xh*yh; Y[5]=s15*yh*zh; Y[6]=0.5f*s5*(3.f*zh*zh-1.f);
  Y[7]=s15*xh*zh; Y[8]=0.5f*s15*(xh*xh-yh*yh);
  float hid[NHID];
  #pragma unroll
  for(int t=0;t<NHID;t++) hid[t] = hidg[(size_t)t*BEs + el];
  const float* hs = h_in + ((long)b*N + src)*DIM;
  float* op = USE_ATOMIC ? (outdst + ((long)b*N + e_dst[el])*DIM) : nullptr;
  float acc[5];
  #pragma unroll
  for(int i=0;i<5;i++) acc[i]=0.f;

  if(vu<12){
    int v=vu;
    do_path_f<0,0,0,12,12,  0,0,   0,   0>(hs,Y,wf,hid,cgl,v,acc);
    do_path_f<1,1,0, 4,12, 12,1, 280,  44>(hs,Y,wf,hid,cgl,v,acc);
    do_path_f<2,2,0, 6,12, 36,4, 516, 396>(hs,Y,wf,hid,cgl,v,acc);
    float r = acc[0]*0.21320071635561044f;
    if(USE_ATOMIC) unsafeAtomicAdd(&op[v], r);
    else outdst[(size_t)v*BEs + el] = r;
  } else if(vu<16){
    int v=vu-12;
    do_path_f<0,1,1,12, 4,  0,1, 144,   1>(hs,Y,wf,hid,cgl,v,acc);
    do_path_f<1,0,1, 4, 4, 12,0, 264,  35>(hs,Y,wf,hid,cgl,v,acc);
    do_path_f<1,2,1, 4, 4, 12,4, 368, 125>(hs,Y,wf,hid,cgl,v,acc);
    do_path_f<1,1,1, 4, 4, 24,1, 400, 179>(hs,Y,wf,hid,cgl,v,acc);
    do_path_f<2,1,1, 6, 4, 36,1, 492, 351>(hs,Y,wf,hid,cgl,v,acc);
    #pragma unroll
    for(int k=0;k<3;k++){
      float r = acc[k]*0.31622776601683794f;
      int d = 12+v*3+k;
      if(USE_ATOMIC) unsafeAtomicAdd(&op[d], r);
      else outdst[(size_t)d*BEs + el] = r;
    }
  } else if(vu<20){
    int v=vu-16;
    do_path_f<1,1,1, 4, 4, 12,1, 328,  53>(hs,Y,wf,hid,cgl,v,acc);
    do_path_f<1,0,1, 4, 4, 24,0, 384, 170>(hs,Y,wf,hid,cgl,v,acc);
    do_path_f<1,2,1, 4, 4, 24,4, 416, 206>(hs,Y,wf,hid,cgl,v,acc);
    do_path_f<2,2,1, 6, 4, 36,4, 588, 421>(hs,Y,wf,hid,cgl,v,acc);
    #pragma unroll
    for(int k=0;k<3;k++){
      float r = acc[k]*0.4082482904638631f;
      int d = 24+v*3+k;
      if(USE_ATOMIC) unsafeAtomicAdd(&op[d], r);
      else outdst[(size_t)d*BEs + el] = r;
    }
  } else {
    int v=vu-20;
    do_path_f<0,2,2,12, 6,  0,4, 192,  10>(hs,Y,wf,hid,cgl,v,acc);
    do_path_f<1,1,2, 4, 6, 12,1, 344,  80>(hs,Y,wf,hid,cgl,v,acc);
    do_path_f<1,2,2, 4, 6, 24,4, 432, 251>(hs,Y,wf,hid,cgl,v,acc);
    do_path_f<2,0,2, 6, 6, 36,0, 456, 326>(hs,Y,wf,hid,cgl,v,acc);
    do_path_f<2,2,2, 6, 6, 36,4, 612, 496>(hs,Y,wf,hid,cgl,v,acc);
    #pragma unroll
    for(int k=0;k<5;k++){
      float r = acc[k]*0.3952847075210474f;
      int d = 36+v*5+k;
      if(USE_ATOMIC) unsafeAtomicAdd(&op[d], r);
      else outdst[(size_t)d*BEs + el] = r;
    }
  }
}

// ---------------- transpose msg[d][BE] -> msgT[el][66] (LDS-tiled) ----------------

__global__ __launch_bounds__(256) void msg_tr_kernel(
  const float* __restrict__ msg, float* __restrict__ msgT, int BE)
{
  __shared__ float tile[DIM*65];
  long e0 = (long)blockIdx.x*64;
  for(int i=threadIdx.x;i<DIM*64;i+=256){
    int d=i>>6, e=i&63;
    long el=e0+e;
    tile[d*65+e] = (el<BE)? msg[(size_t)d*BE+el] : 0.f;
  }
  __syncthreads();
  for(int i=threadIdx.x;i<64*DIM;i+=256){
    int e=i/DIM, d=i-e*DIM;
    long el=e0+e;
    if(el<BE) msgT[(size_t)el*DIM+d] = tile[d*65+e];
  }
}

// ---------------- gather2: one WAVE per node, contiguous msgT rows ----------------

__global__ __launch_bounds__(256) void gather2_kernel(
  const float* __restrict__ msgT, const int* __restrict__ cnt, const int* __restrict__ off,
  const int* __restrict__ elist, float* __restrict__ out, int BN)
{
  int wave = threadIdx.x>>6, lane = threadIdx.x&63;
  long node = (long)blockIdx.x*4 + wave;
  if(node>=BN) return;
  int c = cnt[node], o = off[node];
  float s0=0.f, s1=0.f;
  for(int i=0;i<c;i++){
    int el = elist[o+i];                       // wave-uniform -> scalar load
    const float* mr = msgT + (size_t)el*DIM;
    s0 += mr[lane];                            // 256B contiguous burst
    if(lane<2) s1 += mr[64+lane];
  }
  float* op = out + node*(long)DIM;
  op[lane] += s0;
  if(lane<2) op[64+lane] += s1;
}

// ---------------- norm_act ----------------

__global__ void norm_act_kernel(float* __restrict__ out, int total){
  int idx=blockIdx.x*blockDim.x+threadIdx.x;
  if(idx>=total) return;
  int c = idx % 26; long bn = idx / 26;
  int off, len;
  if(c<12){ off=c; len=1; }
  else if(c<16){ off=12+(c-12)*3; len=3; }
  else if(c<20){ off=24+(c-16)*3; len=3; }
  else { off=36+(c-20)*5; len=5; }
  float* p = out + bn*(long)DIM + off;
  float sum=0.f;
  for(int i=0;i<len;i++){ float v=p[i]; sum+=v*v; }
  float n = sqrtf(sum+1e-12f);
  float sc = 1.f/(1.f+expf(-n));
  for(int i=0;i<len;i++) p[i]*=sc;
}

// ---------------- launch ----------------

extern "C" void kernel_launch(void* const* d_in, const int* in_sizes, int n_in,
                              void* d_out, int out_size, void* d_ws, size_t ws_size,
                              hipStream_t stream)
{
  const float* h       = (const float*)d_in[0];
  const int*   e_src   = (const int*)  d_in[1];
  const int*   e_dst   = (const int*)  d_in[2];
  const float* e_attr  = (const float*)d_in[3];
  const float* lw0     = (const float*)d_in[4];
  const float* lw1o    = (const float*)d_in[5];
  const float* lw1e    = (const float*)d_in[6];
  const float* lw2     = (const float*)d_in[7];
  const float* lb0     = (const float*)d_in[8];
  const float* rw0     = (const float*)d_in[9];
  const float* rw1o    = (const float*)d_in[10];
  const float* rw1e    = (const float*)d_in[11];
  const float* rw2     = (const float*)d_in[12];
  const float* rb0     = (const float*)d_in[13];
  const float* rad_w1  = (const float*)d_in[14];
  const float* rad_w2  = (const float*)d_in[15];

  const int B  = 2;
  const int BE = in_sizes[1];
  const int E  = BE / B;
  const int BN = in_sizes[0] / DIM;
  const int N  = BN / B;

  float* ws   = (float*)d_ws;
  float* h_in = ws;                                   // BN*DIM
  float* cg   = ws + (size_t)BN*DIM;                  // 640
  float* wf   = cg + 640;                             // WNUM*NHID
  float* hidg = wf + WNUM*NHID;                       // NHID*BE
  float* msg  = hidg + (size_t)NHID*BE;               // DIM*BE
  float* msgT = msg + (size_t)DIM*BE;                 // BE*DIM
  int*   cnt  = (int*)(msgT + (size_t)BE*DIM);
  int*   offp = cnt + BN;
  int*   cur  = offp + BN;
  int*   elist= cur + BN;

  size_t need_f = (size_t)BN*DIM + 640 + (size_t)WNUM*NHID
                + (size_t)NHID*BE + 2*(size_t)DIM*BE + 3*(size_t)BN + (size_t)BE;
  bool csr_ok = (ws_size/4) >= need_f + 1024;

  cg_init_kernel<<<NPATH, 128, 0, stream>>>(cg);
  int wfn = WNUM*NHID;
  wf_pack_kernel<<<(wfn+255)/256, 256, 0, stream>>>(rad_w2, wf);
  dim3 hgrid((BE+255)/256, NHID);
  hid_kernel<<<hgrid, 256, 0, stream>>>(e_attr, rad_w1, hidg, BE);
  int totL = BN*DIM;
  linear_kernel<<<(totL+255)/256, 256, 0, stream>>>(h, lw0, lw1o, lw1e, lw2, lb0,
                                                    rw0, rw1o, rw1e, rw2, rb0,
                                                    h_in, (float*)d_out, totL);
  if(csr_ok){
    zero_int_kernel<<<(BN+255)/256, 256, 0, stream>>>(cnt, BN);
    zero_int_kernel<<<(BN+255)/256, 256, 0, stream>>>(cur, BN);
    count_kernel<<<(BE+255)/256, 256, 0, stream>>>(e_dst, cnt, BE, N, E);
    scan_kernel<<<1, 1024, 0, stream>>>(cnt, offp, BN);
    fill_kernel<<<(BE+255)/256, 256, 0, stream>>>(e_dst, offp, cur, elist, BE, N, E);
    dim3 bgrid(26, (BE+255)/256);
    tp_out_kernel<false><<<bgrid, 256, 0, stream>>>(h_in, e_src, e_dst, e_attr,
                                                    hidg, wf, cg, msg, BE, N, E);
    msg_tr_kernel<<<(BE+63)/64, 256, 0, stream>>>(msg, msgT, BE);
    gather2_kernel<<<(BN+3)/4, 256, 0, stream>>>(msgT, cnt, offp, elist, (float*)d_out, BN);
  } else {
    dim3 bgrid(26, (BE+255)/256);
    tp_out_kernel<true><<<bgrid, 256, 0, stream>>>(h_in, e_src, e_dst, e_attr,
                                                   hidg, wf, cg, (float*)d_out, BE, N, E);
  }
  int totN = BN*26;
  norm_act_kernel<<<(totN+255)/256, 256, 0, stream>>>((float*)d_out, totN);
}

// Round 27
// 308.035 us; speedup vs baseline: 1.7082x; 1.1026x over previous
//
#include <hip/hip_runtime.h>
#include <math.h>

#define DIM 66
#define NPATH 17
#define WNUM 648
#define NHID 32

typedef _Float16 h2 __attribute__((ext_vector_type(2)));

// ---------------- CG computation (device, mirrors reference exactly) ----------------

__device__ double dfact(int n){ double f=1.0; for(int i=2;i<=n;i++) f*=(double)i; return f; }

__device__ double su2_cg(int j1,int j2,int j3,int m1,int m2,int m3){
  if(m1+m2!=m3) return 0.0;
  double pre = sqrt((double)(2*j3+1)*dfact(j3+j1-j2)*dfact(j3-j1+j2)*dfact(j1+j2-j3)/dfact(j1+j2+j3+1));
  pre *= sqrt(dfact(j3+m3)*dfact(j3-m3)*dfact(j1-m1)*dfact(j1+m1)*dfact(j2-m2)*dfact(j2+m2));
  double s=0.0;
  for(int k=0;k<=j1+j2-j3;k++){
    int a0=k, a1=j1+j2-j3-k, a2=j1-m1-k, a3=j2+m2-k, a4=j3-j2+m1+k, a5=j3-j1-m2+k;
    if(a0<0||a1<0||a2<0||a3<0||a4<0||a5<0) continue;
    double d = dfact(a0)*dfact(a1)*dfact(a2)*dfact(a3)*dfact(a4)*dfact(a5);
    s += ((k&1)? -1.0:1.0)/d;
  }
  return pre*s;
}

__device__ void u_real_entry(int l, int row, int col, double& re, double& im){
  re=0.0; im=0.0;
  const double sq = 0.7071067811865476;
  int m = row - l;
  if(m>0){
    if(col==l+m) re = ((m&1)? -sq : sq);
    else if(col==l-m) re = sq;
  } else if(m==0){
    if(col==l) re = 1.0;
  } else {
    int am = -m;
    if(col==l+m) im = sq;
    else if(col==l-m) im = ((am&1)? sq : -sq);
  }
}

__constant__ int c_l1[NPATH]   = {0,0,0,1,1,1,1,1,1,1,1,1,2,2,2,2,2};
__constant__ int c_l2[NPATH]   = {0,1,2,0,1,1,1,2,0,1,2,2,0,1,2,2,2};
__constant__ int c_l3[NPATH]   = {0,1,2,1,0,1,2,1,1,1,1,2,2,1,0,1,2};
__constant__ int c_cgoff[NPATH]= {0,1,10,35,44,53,80,125,170,179,206,251,326,351,396,421,496};

__global__ void cg_init_kernel(float* __restrict__ cg_out){
  int p = blockIdx.x;
  int l1=c_l1[p], l2=c_l2[p], l3=c_l3[p];
  int n1=2*l1+1, n2=2*l2+1, n3=2*l3+1;
  int ntot=n1*n2*n3;
  __shared__ double Cc[125];
  __shared__ double red[128];
  int t=threadIdx.x;
  if(t<ntot){
    int i=t/(n2*n3), j=(t/n3)%n2, k=t%n3;
    Cc[t] = su2_cg(l1,l2,l3,i-l1,j-l2,k-l3);
  }
  __syncthreads();
  double Tre=0.0, Tim=0.0;
  if(t<ntot){
    int a=t/(n2*n3), b=(t/n3)%n2, c=t%n3;
    for(int i=0;i<n1;i++)for(int j=0;j<n2;j++)for(int k=0;k<n3;k++){
      double cc=Cc[(i*n2+j)*n3+k];
      if(cc==0.0) continue;
      double u1r,u1i,u2r,u2i,u3r,u3i;
      u_real_entry(l1,a,i,u1r,u1i); u1i=-u1i;
      u_real_entry(l2,b,j,u2r,u2i); u2i=-u2i;
      u_real_entry(l3,c,k,u3r,u3i);
      double pr=u1r*u2r-u1i*u2i, pi=u1r*u2i+u1i*u2r;
      double qr=pr*u3r-pi*u3i,   qi=pr*u3i+pi*u3r;
      Tre+=qr*cc; Tim+=qi*cc;
    }
  }
  red[t]=fabs(Tre); __syncthreads();
  for(int s=64;s>0;s>>=1){ if(t<s) red[t]+=red[t+s]; __syncthreads(); }
  double sar=red[0]; __syncthreads();
  red[t]=fabs(Tim); __syncthreads();
  for(int s=64;s>0;s>>=1){ if(t<s) red[t]+=red[t+s]; __syncthreads(); }
  double sai=red[0]; __syncthreads();
  double chosen = (sar>=sai)? Tre : Tim;
  red[t]=chosen*chosen; __syncthreads();
  for(int s=64;s>0;s>>=1){ if(t<s) red[t]+=red[t+s]; __syncthreads(); }
  double nrm=sqrt(red[0]);
  if(t<ntot) cg_out[c_cgoff[p]+t] = (float)(chosen/nrm);
}

// ------- W -> h2 pairs: wf2[row][16], fold 1/sqrt(32) -------

__global__ void wf2_pack_kernel(const float* __restrict__ w2, h2* __restrict__ wf2){
  int i=blockIdx.x*blockDim.x+threadIdx.x;
  if(i>=WNUM*16) return;
  int nr=i>>4, t2=i&15;
  const float sc = 0.17677669529663687f;
  h2 v;
  v.x = (_Float16)(w2[(2*t2  )*WNUM+nr]*sc);
  v.y = (_Float16)(w2[(2*t2+1)*WNUM+nr]*sc);
  wf2[i]=v;
}

// ------- hid2[t2][el] = {silu(rn*w1[2t2]), silu(rn*w1[2t2+1])} -------

__global__ void hid2_kernel(const float* __restrict__ e_attr, const float* __restrict__ rad_w1,
                            h2* __restrict__ hidg2, int BE){
  int el = blockIdx.x*blockDim.x+threadIdx.x;
  if(el>=BE) return;
  int t2 = blockIdx.y;
  const float* ea = e_attr + (long)el*3;
  float x=ea[0], y=ea[1], z=ea[2];
  float rn = sqrtf(x*x+y*y+z*z)+1e-8f;
  float a0 = rn*rad_w1[2*t2], a1 = rn*rad_w1[2*t2+1];
  h2 v;
  v.x = (_Float16)(a0/(1.f+expf(-a0)));
  v.y = (_Float16)(a1/(1.f+expf(-a1)));
  hidg2[(size_t)t2*BE + el] = v;
}

// ---------------- per-node linears ----------------

__global__ void linear_kernel(const float* __restrict__ h,
  const float* __restrict__ w0i, const float* __restrict__ w1oi, const float* __restrict__ w1ei,
  const float* __restrict__ w2i, const float* __restrict__ b0i,
  const float* __restrict__ w0r, const float* __restrict__ w1or_, const float* __restrict__ w1er,
  const float* __restrict__ w2r, const float* __restrict__ b0r,
  float* __restrict__ h_in, float* __restrict__ out, int total)
{
  int idx=blockIdx.x*blockDim.x+threadIdx.x;
  if(idx>=total) return;
  int d = idx % DIM;
  long bn = idx / DIM;
  const float* hr = h + bn*(long)DIM;
  float s1=0.f, s2=0.f, o1, o2;
  if(d<12){
    #pragma unroll
    for(int u=0;u<12;u++){ float xv=hr[u]; s1+=xv*w0i[u*12+d]; s2+=xv*w0r[u*12+d]; }
    const float r = 0.28867513459481287f;
    o1 = s1*r + b0i[d]; o2 = s2*r + b0r[d];
  } else if(d<24){
    int rel=d-12, v=rel/3, i=rel%3;
    #pragma unroll
    for(int u=0;u<4;u++){ float xv=hr[12+u*3+i]; s1+=xv*w1oi[u*4+v]; s2+=xv*w1or_[u*4+v]; }
    o1=s1*0.5f; o2=s2*0.5f;
  } else if(d<36){
    int rel=d-24, v=rel/3, i=rel%3;
    #pragma unroll
    for(int u=0;u<4;u++){ float xv=hr[24+u*3+i]; s1+=xv*w1ei[u*4+v]; s2+=xv*w1er[u*4+v]; }
    o1=s1*0.5f; o2=s2*0.5f;
  } else {
    int rel=d-36, v=rel/5, i=rel%5;
    #pragma unroll
    for(int u=0;u<6;u++){ float xv=hr[36+u*5+i]; s1+=xv*w2i[u*6+v]; s2+=xv*w2r[u*6+v]; }
    const float r=0.4082482904638631f;
    o1=s1*r; o2=s2*r;
  }
  h_in[idx]=o1; out[idx]=o2;
}

// ---------------- CSR build ----------------

__global__ void count_kernel(const int* __restrict__ e_dst, int* __restrict__ cnt, int BE, int N, int E){
  int el=blockIdx.x*blockDim.x+threadIdx.x;
  if(el>=BE) return;
  int b=el/E;
  atomicAdd(&cnt[b*N+e_dst[el]], 1);
}

__global__ void scan_kernel(const int* __restrict__ cnt, int* __restrict__ off, int BN){
  __shared__ int part[1024];
  int t=threadIdx.x;
  int items=(BN+1023)>>10;
  int base=t*items;
  int s=0;
  for(int i=0;i<items;i++){ int idx=base+i; if(idx<BN) s+=cnt[idx]; }
  part[t]=s; __syncthreads();
  for(int d=1;d<1024;d<<=1){
    int v=(t>=d)?part[t-d]:0; __syncthreads();
    part[t]+=v; __syncthreads();
  }
  int run=(t==0)?0:part[t-1];
  for(int i=0;i<items;i++){ int idx=base+i; if(idx<BN){ off[idx]=run; run+=cnt[idx]; } }
}

__global__ void fill_kernel(const int* __restrict__ e_dst, const int* __restrict__ off,
                            int* __restrict__ cursor, int* __restrict__ elist, int BE, int N, int E){
  int el=blockIdx.x*blockDim.x+threadIdx.x;
  if(el>=BE) return;
  int b=el/E;
  int fd=b*N+e_dst[el];
  int pos=atomicAdd(&cursor[fd],1);
  elist[off[fd]+pos]=el;
}

// ---------------- Kernel B: fused TP per (edge, v-unit); fdot2 weight dots ----------------

template<int L1_,int L2_,int L3_,int MUL1,int MULO,int XOFF,int YOFF,int WOFF,int CGOFF>
__device__ __forceinline__ void do_path_f(const float* __restrict__ hs, const float* Y,
  const h2* __restrict__ wf2, const h2* __restrict__ hid2,
  const float* __restrict__ cgl, int v, float* acc)
{
  constexpr int N1=2*L1_+1, N2=2*L2_+1, N3=2*L3_+1;
  float M[N1*N3];
  #pragma unroll
  for(int i=0;i<N1;i++){
    #pragma unroll
    for(int k=0;k<N3;k++){
      float s=0.f;
      #pragma unroll
      for(int j=0;j<N2;j++) s += Y[YOFF+j]*cgl[CGOFF+(i*N2+j)*N3+k];
      M[i*N3+k]=s;
    }
  }
  #pragma unroll
  for(int u=0;u<MUL1;u++){
    const h2* wr = wf2 + (WOFF+u*MULO+v)*16;   // block-uniform address
    float w=0.f;
    #pragma unroll
    for(int t2=0;t2<16;t2++) w = __builtin_amdgcn_fdot2(wr[t2], hid2[t2], w, false);
    #pragma unroll
    for(int k=0;k<N3;k++){
      float z=0.f;
      #pragma unroll
      for(int i=0;i<N1;i++) z += hs[XOFF+u*N1+i]*M[i*N3+k];
      acc[k] += z*w;
    }
  }
}

template<bool USE_ATOMIC>
__global__ __launch_bounds__(256) void tp_out_kernel(
  const float* __restrict__ h_in, const int* __restrict__ e_src, const int* __restrict__ e_dst,
  const float* __restrict__ e_attr, const h2* __restrict__ hidg2, const h2* __restrict__ wf2,
  const float* __restrict__ cg, float* __restrict__ outdst, int BE, int N, int E)
{
  __shared__ float cgl[640];
  for(int i=threadIdx.x;i<621;i+=256) cgl[i]=cg[i];
  __syncthreads();
  long el = (long)blockIdx.y*256 + threadIdx.x;
  if(el>=BE) return;
  int vu = blockIdx.x;
  size_t BEs = (size_t)BE;
  int b = (int)(el / E);
  int src = e_src[el];
  const float* ea = e_attr + el*3;
  float x=ea[0], y=ea[1], z=ea[2];
  float rn = sqrtf(x*x+y*y+z*z) + 1e-8f;
  float xh=x/rn, yh=y/rn, zh=z/rn;
  float Y[9];
  const float s3=1.7320508075688772f, s5=2.23606797749979f, s15=3.872983346207417f;
  Y[0]=1.f; Y[1]=s3*yh; Y[2]=s3*zh; Y[3]=s3*xh;
  Y[4]=s15*xh*yh; Y[5]=s15*yh*zh; Y[6]=0.5f*s5*(3.f*zh*zh-1.f);
  Y[7]=s15*xh*zh; Y[8]=0.5f*s15*(xh*xh-yh*yh);
  h2 hid2[16];
  #pragma unroll
  for(int t2=0;t2<16;t2++) hid2[t2] = hidg2[(size_t)t2*BEs + el];   // coalesced 4B
  const float* hs = h_in + ((long)b*N + src)*DIM;
  float* op = USE_ATOMIC ? (outdst + ((long)b*N + e_dst[el])*DIM) : nullptr;
  float acc[5];
  #pragma unroll
  for(int i=0;i<5;i++) acc[i]=0.f;

  if(vu<12){
    int v=vu;
    do_path_f<0,0,0,12,12,  0,0,   0,   0>(hs,Y,wf2,hid2,cgl,v,acc);
    do_path_f<1,1,0, 4,12, 12,1, 280,  44>(hs,Y,wf2,hid2,cgl,v,acc);
    do_path_f<2,2,0, 6,12, 36,4, 516, 396>(hs,Y,wf2,hid2,cgl,v,acc);
    float r = acc[0]*0.21320071635561044f;
    if(USE_ATOMIC) unsafeAtomicAdd(&op[v], r);
    else outdst[(size_t)v*BEs + el] = r;
  } else if(vu<16){
    int v=vu-12;
    do_path_f<0,1,1,12, 4,  0,1, 144,   1>(hs,Y,wf2,hid2,cgl,v,acc);
    do_path_f<1,0,1, 4, 4, 12,0, 264,  35>(hs,Y,wf2,hid2,cgl,v,acc);
    do_path_f<1,2,1, 4, 4, 12,4, 368, 125>(hs,Y,wf2,hid2,cgl,v,acc);
    do_path_f<1,1,1, 4, 4, 24,1, 400, 179>(hs,Y,wf2,hid2,cgl,v,acc);
    do_path_f<2,1,1, 6, 4, 36,1, 492, 351>(hs,Y,wf2,hid2,cgl,v,acc);
    #pragma unroll
    for(int k=0;k<3;k++){
      float r = acc[k]*0.31622776601683794f;
      int d = 12+v*3+k;
      if(USE_ATOMIC) unsafeAtomicAdd(&op[d], r);
      else outdst[(size_t)d*BEs + el] = r;
    }
  } else if(vu<20){
    int v=vu-16;
    do_path_f<1,1,1, 4, 4, 12,1, 328,  53>(hs,Y,wf2,hid2,cgl,v,acc);
    do_path_f<1,0,1, 4, 4, 24,0, 384, 170>(hs,Y,wf2,hid2,cgl,v,acc);
    do_path_f<1,2,1, 4, 4, 24,4, 416, 206>(hs,Y,wf2,hid2,cgl,v,acc);
    do_path_f<2,2,1, 6, 4, 36,4, 588, 421>(hs,Y,wf2,hid2,cgl,v,acc);
    #pragma unroll
    for(int k=0;k<3;k++){
      float r = acc[k]*0.4082482904638631f;
      int d = 24+v*3+k;
      if(USE_ATOMIC) unsafeAtomicAdd(&op[d], r);
      else outdst[(size_t)d*BEs + el] = r;
    }
  } else {
    int v=vu-20;
    do_path_f<0,2,2,12, 6,  0,4, 192,  10>(hs,Y,wf2,hid2,cgl,v,acc);
    do_path_f<1,1,2, 4, 6, 12,1, 344,  80>(hs,Y,wf2,hid2,cgl,v,acc);
    do_path_f<1,2,2, 4, 6, 24,4, 432, 251>(hs,Y,wf2,hid2,cgl,v,acc);
    do_path_f<2,0,2, 6, 6, 36,0, 456, 326>(hs,Y,wf2,hid2,cgl,v,acc);
    do_path_f<2,2,2, 6, 6, 36,4, 612, 496>(hs,Y,wf2,hid2,cgl,v,acc);
    #pragma unroll
    for(int k=0;k<5;k++){
      float r = acc[k]*0.3952847075210474f;
      int d = 36+v*5+k;
      if(USE_ATOMIC) unsafeAtomicAdd(&op[d], r);
      else outdst[(size_t)d*BEs + el] = r;
    }
  }
}

// ---------------- transpose msg[d][BE] -> msgT[el][66] (LDS-tiled) ----------------

__global__ __launch_bounds__(256) void msg_tr_kernel(
  const float* __restrict__ msg, float* __restrict__ msgT, int BE)
{
  __shared__ float tile[DIM*65];
  long e0 = (long)blockIdx.x*64;
  for(int i=threadIdx.x;i<DIM*64;i+=256){
    int d=i>>6, e=i&63;
    long el=e0+e;
    tile[d*65+e] = (el<BE)? msg[(size_t)d*BE+el] : 0.f;
  }
  __syncthreads();
  for(int i=threadIdx.x;i<64*DIM;i+=256){
    int e=i/DIM, d=i-e*DIM;
    long el=e0+e;
    if(el<BE) msgT[(size_t)el*DIM+d] = tile[d*65+e];
  }
}

// ---------------- gather2: one WAVE per node, contiguous msgT rows ----------------

__global__ __launch_bounds__(256) void gather2_kernel(
  const float* __restrict__ msgT, const int* __restrict__ cnt, const int* __restrict__ off,
  const int* __restrict__ elist, float* __restrict__ out, int BN)
{
  int wave = threadIdx.x>>6, lane = threadIdx.x&63;
  long node = (long)blockIdx.x*4 + wave;
  if(node>=BN) return;
  int c = cnt[node], o = off[node];
  float s0=0.f, s1=0.f;
  for(int i=0;i<c;i++){
    int el = elist[o+i];
    const float* mr = msgT + (size_t)el*DIM;
    s0 += mr[lane];
    if(lane<2) s1 += mr[64+lane];
  }
  float* op = out + node*(long)DIM;
  op[lane] += s0;
  if(lane<2) op[64+lane] += s1;
}

// ---------------- norm_act ----------------

__global__ void norm_act_kernel(float* __restrict__ out, int total){
  int idx=blockIdx.x*blockDim.x+threadIdx.x;
  if(idx>=total) return;
  int c = idx % 26; long bn = idx / 26;
  int off, len;
  if(c<12){ off=c; len=1; }
  else if(c<16){ off=12+(c-12)*3; len=3; }
  else if(c<20){ off=24+(c-16)*3; len=3; }
  else { off=36+(c-20)*5; len=5; }
  float* p = out + bn*(long)DIM + off;
  float sum=0.f;
  for(int i=0;i<len;i++){ float v=p[i]; sum+=v*v; }
  float n = sqrtf(sum+1e-12f);
  float sc = 1.f/(1.f+expf(-n));
  for(int i=0;i<len;i++) p[i]*=sc;
}

// ---------------- launch ----------------

extern "C" void kernel_launch(void* const* d_in, const int* in_sizes, int n_in,
                              void* d_out, int out_size, void* d_ws, size_t ws_size,
                              hipStream_t stream)
{
  const float* h       = (const float*)d_in[0];
  const int*   e_src   = (const int*)  d_in[1];
  const int*   e_dst   = (const int*)  d_in[2];
  const float* e_attr  = (const float*)d_in[3];
  const float* lw0     = (const float*)d_in[4];
  const float* lw1o    = (const float*)d_in[5];
  const float* lw1e    = (const float*)d_in[6];
  const float* lw2     = (const float*)d_in[7];
  const float* lb0     = (const float*)d_in[8];
  const float* rw0     = (const float*)d_in[9];
  const float* rw1o    = (const float*)d_in[10];
  const float* rw1e    = (const float*)d_in[11];
  const float* rw2     = (const float*)d_in[12];
  const float* rb0     = (const float*)d_in[13];
  const float* rad_w1  = (const float*)d_in[14];
  const float* rad_w2  = (const float*)d_in[15];

  const int B  = 2;
  const int BE = in_sizes[1];
  const int E  = BE / B;
  const int BN = in_sizes[0] / DIM;
  const int N  = BN / B;

  float* ws   = (float*)d_ws;
  float* h_in = ws;                                   // BN*DIM
  float* cg   = ws + (size_t)BN*DIM;                  // 640
  h2*    wf2  = (h2*)(cg + 640);                      // WNUM*16 h2
  h2*    hidg2= wf2 + (size_t)WNUM*16;                // 16*BE h2
  float* msg  = (float*)(hidg2 + (size_t)16*BE);      // DIM*BE f32
  float* msgT = msg + (size_t)DIM*BE;                 // BE*DIM f32
  int*   cnt  = (int*)(msgT + (size_t)BE*DIM);
  int*   cur  = cnt + BN;                             // adjacent -> one memset
  int*   offp = cur + BN;
  int*   elist= offp + BN;

  size_t need_f = (size_t)BN*DIM + 640 + (size_t)WNUM*16 + (size_t)16*BE
                + 2*(size_t)DIM*BE + 3*(size_t)BN + (size_t)BE;
  bool csr_ok = (ws_size/4) >= need_f + 1024;

  cg_init_kernel<<<NPATH, 128, 0, stream>>>(cg);
  int wfn = WNUM*16;
  wf2_pack_kernel<<<(wfn+255)/256, 256, 0, stream>>>(rad_w2, wf2);
  dim3 hgrid((BE+255)/256, 16);
  hid2_kernel<<<hgrid, 256, 0, stream>>>(e_attr, rad_w1, hidg2, BE);
  int totL = BN*DIM;
  linear_kernel<<<(totL+255)/256, 256, 0, stream>>>(h, lw0, lw1o, lw1e, lw2, lb0,
                                                    rw0, rw1o, rw1e, rw2, rb0,
                                                    h_in, (float*)d_out, totL);
  if(csr_ok){
    hipMemsetAsync(cnt, 0, 2*(size_t)BN*sizeof(int), stream);   // cnt + cur
    count_kernel<<<(BE+255)/256, 256, 0, stream>>>(e_dst, cnt, BE, N, E);
    scan_kernel<<<1, 1024, 0, stream>>>(cnt, offp, BN);
    fill_kernel<<<(BE+255)/256, 256, 0, stream>>>(e_dst, offp, cur, elist, BE, N, E);
    dim3 bgrid(26, (BE+255)/256);
    tp_out_kernel<false><<<bgrid, 256, 0, stream>>>(h_in, e_src, e_dst, e_attr,
                                                    hidg2, wf2, cg, msg, BE, N, E);
    msg_tr_kernel<<<(BE+63)/64, 256, 0, stream>>>(msg, msgT, BE);
    gather2_kernel<<<(BN+3)/4, 256, 0, stream>>>(msgT, cnt, offp, elist, (float*)d_out, BN);
  } else {
    dim3 bgrid(26, (BE+255)/256);
    tp_out_kernel<true><<<bgrid, 256, 0, stream>>>(h_in, e_src, e_dst, e_attr,
                                                   hidg2, wf2, cg, (float*)d_out, BE, N, E);
  }
  int totN = BN*26;
  norm_act_kernel<<<(totN+255)/256, 256, 0, stream>>>((float*)d_out, totN);
}

// Round 28
// 297.349 us; speedup vs baseline: 1.7696x; 1.0359x over previous
//
#include <hip/hip_runtime.h>
#include <math.h>

#define DIM 66
#define NPATH 17
#define WNUM 648
#define NHID 32

typedef _Float16 h2 __attribute__((ext_vector_type(2)));

// ---------------- CG computation (device, mirrors reference exactly) ----------------

__device__ double dfact(int n){ double f=1.0; for(int i=2;i<=n;i++) f*=(double)i; return f; }

__device__ double su2_cg(int j1,int j2,int j3,int m1,int m2,int m3){
  if(m1+m2!=m3) return 0.0;
  double pre = sqrt((double)(2*j3+1)*dfact(j3+j1-j2)*dfact(j3-j1+j2)*dfact(j1+j2-j3)/dfact(j1+j2+j3+1));
  pre *= sqrt(dfact(j3+m3)*dfact(j3-m3)*dfact(j1-m1)*dfact(j1+m1)*dfact(j2-m2)*dfact(j2+m2));
  double s=0.0;
  for(int k=0;k<=j1+j2-j3;k++){
    int a0=k, a1=j1+j2-j3-k, a2=j1-m1-k, a3=j2+m2-k, a4=j3-j2+m1+k, a5=j3-j1-m2+k;
    if(a0<0||a1<0||a2<0||a3<0||a4<0||a5<0) continue;
    double d = dfact(a0)*dfact(a1)*dfact(a2)*dfact(a3)*dfact(a4)*dfact(a5);
    s += ((k&1)? -1.0:1.0)/d;
  }
  return pre*s;
}

__device__ void u_real_entry(int l, int row, int col, double& re, double& im){
  re=0.0; im=0.0;
  const double sq = 0.7071067811865476;
  int m = row - l;
  if(m>0){
    if(col==l+m) re = ((m&1)? -sq : sq);
    else if(col==l-m) re = sq;
  } else if(m==0){
    if(col==l) re = 1.0;
  } else {
    int am = -m;
    if(col==l+m) im = sq;
    else if(col==l-m) im = ((am&1)? sq : -sq);
  }
}

__constant__ int c_l1[NPATH]   = {0,0,0,1,1,1,1,1,1,1,1,1,2,2,2,2,2};
__constant__ int c_l2[NPATH]   = {0,1,2,0,1,1,1,2,0,1,2,2,0,1,2,2,2};
__constant__ int c_l3[NPATH]   = {0,1,2,1,0,1,2,1,1,1,1,2,2,1,0,1,2};
__constant__ int c_cgoff[NPATH]= {0,1,10,35,44,53,80,125,170,179,206,251,326,351,396,421,496};

__global__ void cg_init_kernel(float* __restrict__ cg_out){
  int p = blockIdx.x;
  int l1=c_l1[p], l2=c_l2[p], l3=c_l3[p];
  int n1=2*l1+1, n2=2*l2+1, n3=2*l3+1;
  int ntot=n1*n2*n3;
  __shared__ double Cc[125];
  __shared__ double red[128];
  int t=threadIdx.x;
  if(t<ntot){
    int i=t/(n2*n3), j=(t/n3)%n2, k=t%n3;
    Cc[t] = su2_cg(l1,l2,l3,i-l1,j-l2,k-l3);
  }
  __syncthreads();
  double Tre=0.0, Tim=0.0;
  if(t<ntot){
    int a=t/(n2*n3), b=(t/n3)%n2, c=t%n3;
    for(int i=0;i<n1;i++)for(int j=0;j<n2;j++)for(int k=0;k<n3;k++){
      double cc=Cc[(i*n2+j)*n3+k];
      if(cc==0.0) continue;
      double u1r,u1i,u2r,u2i,u3r,u3i;
      u_real_entry(l1,a,i,u1r,u1i); u1i=-u1i;
      u_real_entry(l2,b,j,u2r,u2i); u2i=-u2i;
      u_real_entry(l3,c,k,u3r,u3i);
      double pr=u1r*u2r-u1i*u2i, pi=u1r*u2i+u1i*u2r;
      double qr=pr*u3r-pi*u3i,   qi=pr*u3i+pi*u3r;
      Tre+=qr*cc; Tim+=qi*cc;
    }
  }
  red[t]=fabs(Tre); __syncthreads();
  for(int s=64;s>0;s>>=1){ if(t<s) red[t]+=red[t+s]; __syncthreads(); }
  double sar=red[0]; __syncthreads();
  red[t]=fabs(Tim); __syncthreads();
  for(int s=64;s>0;s>>=1){ if(t<s) red[t]+=red[t+s]; __syncthreads(); }
  double sai=red[0]; __syncthreads();
  double chosen = (sar>=sai)? Tre : Tim;
  red[t]=chosen*chosen; __syncthreads();
  for(int s=64;s>0;s>>=1){ if(t<s) red[t]+=red[t+s]; __syncthreads(); }
  double nrm=sqrt(red[0]);
  if(t<ntot) cg_out[c_cgoff[p]+t] = (float)(chosen/nrm);
}

// ------- W -> h2 pairs: wf2[row][16], fold 1/sqrt(32) -------

__global__ void wf2_pack_kernel(const float* __restrict__ w2, h2* __restrict__ wf2){
  int i=blockIdx.x*blockDim.x+threadIdx.x;
  if(i>=WNUM*16) return;
  int nr=i>>4, t2=i&15;
  const float sc = 0.17677669529663687f;
  h2 v;
  v.x = (_Float16)(w2[(2*t2  )*WNUM+nr]*sc);
  v.y = (_Float16)(w2[(2*t2+1)*WNUM+nr]*sc);
  wf2[i]=v;
}

// ------- hid2[t2][el] -------

__global__ void hid2_kernel(const float* __restrict__ e_attr, const float* __restrict__ rad_w1,
                            h2* __restrict__ hidg2, int BE){
  int el = blockIdx.x*blockDim.x+threadIdx.x;
  if(el>=BE) return;
  int t2 = blockIdx.y;
  const float* ea = e_attr + (long)el*3;
  float x=ea[0], y=ea[1], z=ea[2];
  float rn = sqrtf(x*x+y*y+z*z)+1e-8f;
  float a0 = rn*rad_w1[2*t2], a1 = rn*rad_w1[2*t2+1];
  h2 v;
  v.x = (_Float16)(a0/(1.f+expf(-a0)));
  v.y = (_Float16)(a1/(1.f+expf(-a1)));
  hidg2[(size_t)t2*BE + el] = v;
}

// ---------------- per-node linears ----------------

__global__ void linear_kernel(const float* __restrict__ h,
  const float* __restrict__ w0i, const float* __restrict__ w1oi, const float* __restrict__ w1ei,
  const float* __restrict__ w2i, const float* __restrict__ b0i,
  const float* __restrict__ w0r, const float* __restrict__ w1or_, const float* __restrict__ w1er,
  const float* __restrict__ w2r, const float* __restrict__ b0r,
  float* __restrict__ h_in, float* __restrict__ out, int total)
{
  int idx=blockIdx.x*blockDim.x+threadIdx.x;
  if(idx>=total) return;
  int d = idx % DIM;
  long bn = idx / DIM;
  const float* hr = h + bn*(long)DIM;
  float s1=0.f, s2=0.f, o1, o2;
  if(d<12){
    #pragma unroll
    for(int u=0;u<12;u++){ float xv=hr[u]; s1+=xv*w0i[u*12+d]; s2+=xv*w0r[u*12+d]; }
    const float r = 0.28867513459481287f;
    o1 = s1*r + b0i[d]; o2 = s2*r + b0r[d];
  } else if(d<24){
    int rel=d-12, v=rel/3, i=rel%3;
    #pragma unroll
    for(int u=0;u<4;u++){ float xv=hr[12+u*3+i]; s1+=xv*w1oi[u*4+v]; s2+=xv*w1or_[u*4+v]; }
    o1=s1*0.5f; o2=s2*0.5f;
  } else if(d<36){
    int rel=d-24, v=rel/3, i=rel%3;
    #pragma unroll
    for(int u=0;u<4;u++){ float xv=hr[24+u*3+i]; s1+=xv*w1ei[u*4+v]; s2+=xv*w1er[u*4+v]; }
    o1=s1*0.5f; o2=s2*0.5f;
  } else {
    int rel=d-36, v=rel/5, i=rel%5;
    #pragma unroll
    for(int u=0;u<6;u++){ float xv=hr[36+u*5+i]; s1+=xv*w2i[u*6+v]; s2+=xv*w2r[u*6+v]; }
    const float r=0.4082482904638631f;
    o1=s1*r; o2=s2*r;
  }
  h_in[idx]=o1; out[idx]=o2;
}

// ---------------- CSR build ----------------

__global__ void count_kernel(const int* __restrict__ e_dst, int* __restrict__ cnt, int BE, int N, int E){
  int el=blockIdx.x*blockDim.x+threadIdx.x;
  if(el>=BE) return;
  int b=el/E;
  atomicAdd(&cnt[b*N+e_dst[el]], 1);
}

__global__ void scan_kernel(const int* __restrict__ cnt, int* __restrict__ off, int BN){
  __shared__ int part[1024];
  int t=threadIdx.x;
  int items=(BN+1023)>>10;
  int base=t*items;
  int s=0;
  for(int i=0;i<items;i++){ int idx=base+i; if(idx<BN) s+=cnt[idx]; }
  part[t]=s; __syncthreads();
  for(int d=1;d<1024;d<<=1){
    int v=(t>=d)?part[t-d]:0; __syncthreads();
    part[t]+=v; __syncthreads();
  }
  int run=(t==0)?0:part[t-1];
  for(int i=0;i<items;i++){ int idx=base+i; if(idx<BN){ off[idx]=run; run+=cnt[idx]; } }
}

__global__ void fill_kernel(const int* __restrict__ e_dst, const int* __restrict__ off,
                            int* __restrict__ cursor, int* __restrict__ elist, int BE, int N, int E){
  int el=blockIdx.x*blockDim.x+threadIdx.x;
  if(el>=BE) return;
  int b=el/E;
  int fd=b*N+e_dst[el];
  int pos=atomicAdd(&cursor[fd],1);
  elist[off[fd]+pos]=el;
}

// ---------------- Kernel B: fused TP per (edge, v-unit); fdot2 weight dots ----------------

template<int L1_,int L2_,int L3_,int MUL1,int MULO,int XOFF,int YOFF,int WOFF,int CGOFF>
__device__ __forceinline__ void do_path_f(const float* __restrict__ hs, const float* Y,
  const h2* __restrict__ wf2, const h2* __restrict__ hid2,
  const float* __restrict__ cgl, int v, float* acc)
{
  constexpr int N1=2*L1_+1, N2=2*L2_+1, N3=2*L3_+1;
  float M[N1*N3];
  #pragma unroll
  for(int i=0;i<N1;i++){
    #pragma unroll
    for(int k=0;k<N3;k++){
      float s=0.f;
      #pragma unroll
      for(int j=0;j<N2;j++) s += Y[YOFF+j]*cgl[CGOFF+(i*N2+j)*N3+k];
      M[i*N3+k]=s;
    }
  }
  #pragma unroll
  for(int u=0;u<MUL1;u++){
    const h2* wr = wf2 + (WOFF+u*MULO+v)*16;
    float w=0.f;
    #pragma unroll
    for(int t2=0;t2<16;t2++) w = __builtin_amdgcn_fdot2(wr[t2], hid2[t2], w, false);
    #pragma unroll
    for(int k=0;k<N3;k++){
      float z=0.f;
      #pragma unroll
      for(int i=0;i<N1;i++) z += hs[XOFF+u*N1+i]*M[i*N3+k];
      acc[k] += z*w;
    }
  }
}

template<bool USE_ATOMIC>
__global__ __launch_bounds__(256) void tp_out_kernel(
  const float* __restrict__ h_in, const int* __restrict__ e_src, const int* __restrict__ e_dst,
  const float* __restrict__ e_attr, const h2* __restrict__ hidg2, const h2* __restrict__ wf2,
  const float* __restrict__ cg, float* __restrict__ outat, _Float16* __restrict__ msgh,
  int BE, int N, int E)
{
  __shared__ float cgl[640];
  for(int i=threadIdx.x;i<621;i+=256) cgl[i]=cg[i];
  __syncthreads();
  long el = (long)blockIdx.y*256 + threadIdx.x;
  if(el>=BE) return;
  int vu = blockIdx.x;
  size_t BEs = (size_t)BE;
  int b = (int)(el / E);
  int src = e_src[el];
  const float* ea = e_attr + el*3;
  float x=ea[0], y=ea[1], z=ea[2];
  float rn = sqrtf(x*x+y*y+z*z) + 1e-8f;
  float xh=x/rn, yh=y/rn, zh=z/rn;
  float Y[9];
  const float s3=1.7320508075688772f, s5=2.23606797749979f, s15=3.872983346207417f;
  Y[0]=1.f; Y[1]=s3*yh; Y[2]=s3*zh; Y[3]=s3*xh;
  Y[4]=s15*xh*yh; Y[5]=s15*yh*zh; Y[6]=0.5f*s5*(3.f*zh*zh-1.f);
  Y[7]=s15*xh*zh; Y[8]=0.5f*s15*(xh*xh-yh*yh);
  h2 hid2[16];
  #pragma unroll
  for(int t2=0;t2<16;t2++) hid2[t2] = hidg2[(size_t)t2*BEs + el];
  const float* hs = h_in + ((long)b*N + src)*DIM;
  float* op = USE_ATOMIC ? (outat + ((long)b*N + e_dst[el])*DIM) : nullptr;
  float acc[5];
  #pragma unroll
  for(int i=0;i<5;i++) acc[i]=0.f;

  if(vu<12){
    int v=vu;
    do_path_f<0,0,0,12,12,  0,0,   0,   0>(hs,Y,wf2,hid2,cgl,v,acc);
    do_path_f<1,1,0, 4,12, 12,1, 280,  44>(hs,Y,wf2,hid2,cgl,v,acc);
    do_path_f<2,2,0, 6,12, 36,4, 516, 396>(hs,Y,wf2,hid2,cgl,v,acc);
    float r = acc[0]*0.21320071635561044f;
    if(USE_ATOMIC) unsafeAtomicAdd(&op[v], r);
    else msgh[(size_t)v*BEs + el] = (_Float16)r;
  } else if(vu<16){
    int v=vu-12;
    do_path_f<0,1,1,12, 4,  0,1, 144,   1>(hs,Y,wf2,hid2,cgl,v,acc);
    do_path_f<1,0,1, 4, 4, 12,0, 264,  35>(hs,Y,wf2,hid2,cgl,v,acc);
    do_path_f<1,2,1, 4, 4, 12,4, 368, 125>(hs,Y,wf2,hid2,cgl,v,acc);
    do_path_f<1,1,1, 4, 4, 24,1, 400, 179>(hs,Y,wf2,hid2,cgl,v,acc);
    do_path_f<2,1,1, 6, 4, 36,1, 492, 351>(hs,Y,wf2,hid2,cgl,v,acc);
    #pragma unroll
    for(int k=0;k<3;k++){
      float r = acc[k]*0.31622776601683794f;
      int d = 12+v*3+k;
      if(USE_ATOMIC) unsafeAtomicAdd(&op[d], r);
      else msgh[(size_t)d*BEs + el] = (_Float16)r;
    }
  } else if(vu<20){
    int v=vu-16;
    do_path_f<1,1,1, 4, 4, 12,1, 328,  53>(hs,Y,wf2,hid2,cgl,v,acc);
    do_path_f<1,0,1, 4, 4, 24,0, 384, 170>(hs,Y,wf2,hid2,cgl,v,acc);
    do_path_f<1,2,1, 4, 4, 24,4, 416, 206>(hs,Y,wf2,hid2,cgl,v,acc);
    do_path_f<2,2,1, 6, 4, 36,4, 588, 421>(hs,Y,wf2,hid2,cgl,v,acc);
    #pragma unroll
    for(int k=0;k<3;k++){
      float r = acc[k]*0.4082482904638631f;
      int d = 24+v*3+k;
      if(USE_ATOMIC) unsafeAtomicAdd(&op[d], r);
      else msgh[(size_t)d*BEs + el] = (_Float16)r;
    }
  } else {
    int v=vu-20;
    do_path_f<0,2,2,12, 6,  0,4, 192,  10>(hs,Y,wf2,hid2,cgl,v,acc);
    do_path_f<1,1,2, 4, 6, 12,1, 344,  80>(hs,Y,wf2,hid2,cgl,v,acc);
    do_path_f<1,2,2, 4, 6, 24,4, 432, 251>(hs,Y,wf2,hid2,cgl,v,acc);
    do_path_f<2,0,2, 6, 6, 36,0, 456, 326>(hs,Y,wf2,hid2,cgl,v,acc);
    do_path_f<2,2,2, 6, 6, 36,4, 612, 496>(hs,Y,wf2,hid2,cgl,v,acc);
    #pragma unroll
    for(int k=0;k<5;k++){
      float r = acc[k]*0.3952847075210474f;
      int d = 36+v*5+k;
      if(USE_ATOMIC) unsafeAtomicAdd(&op[d], r);
      else msgh[(size_t)d*BEs + el] = (_Float16)r;
    }
  }
}

// ---------------- transpose msgh[d][BE] -> msgT[el][66] (f16, LDS-tiled) ----------------

__global__ __launch_bounds__(256) void msg_tr_kernel(
  const _Float16* __restrict__ msgh, _Float16* __restrict__ msgT, int BE)
{
  __shared__ _Float16 tile[DIM*66];
  long e0 = (long)blockIdx.x*64;
  for(int i=threadIdx.x;i<DIM*64;i+=256){
    int d=i>>6, e=i&63;
    long el=e0+e;
    tile[d*66+e] = (el<BE)? msgh[(size_t)d*BE+el] : (_Float16)0.f;
  }
  __syncthreads();
  for(int i=threadIdx.x;i<64*DIM;i+=256){
    int e=i/DIM, d=i-e*DIM;
    long el=e0+e;
    if(el<BE) msgT[(size_t)el*DIM+d] = tile[d*66+e];
  }
}

// ---------------- gather2 + fused norm_act: one WAVE per node ----------------
// Wave accumulates all 66 channels, adds residual (already in out), stages the
// totals in a per-wave LDS row (wave-lockstep, no barrier), computes per-irrep
// norm + silu-gate, writes FINAL output.

__global__ __launch_bounds__(256) void gather2_kernel(
  const _Float16* __restrict__ msgT, const int* __restrict__ cnt, const int* __restrict__ off,
  const int* __restrict__ elist, float* __restrict__ out, int BN)
{
  __shared__ float tot[4][DIM];
  int wave = threadIdx.x>>6, lane = threadIdx.x&63;
  long node = (long)blockIdx.x*4 + wave;
  if(node>=BN) return;
  int c = cnt[node], o = off[node];
  float s0=0.f, s1=0.f;
  for(int i=0;i<c;i++){
    int el = elist[o+i];
    const _Float16* mr = msgT + (size_t)el*DIM;
    s0 += (float)mr[lane];
    if(lane<2) s1 += (float)mr[64+lane];
  }
  float* op = out + node*(long)DIM;
  float t0 = op[lane] + s0;
  tot[wave][lane] = t0;
  float t1 = 0.f;
  if(lane<2){ t1 = op[64+lane] + s1; tot[wave][64+lane] = t1; }
  // wave-lockstep: all LDS writes above complete before reads below (single wave)
  // channel for d=lane
  {
    int d = lane, offc, len;
    if(d<12){ offc=d; len=1; }
    else if(d<24){ offc=12+((d-12)/3)*3; len=3; }
    else if(d<36){ offc=24+((d-24)/3)*3; len=3; }
    else { offc=36+((d-36)/5)*5; len=5; }
    float ss=0.f;
    for(int i=0;i<len;i++){ float v=tot[wave][offc+i]; ss+=v*v; }
    float n = sqrtf(ss+1e-12f);
    float sc = 1.f/(1.f+expf(-n));
    op[d] = t0*sc;
  }
  if(lane<2){
    int d = 64+lane;                       // in segment 36+5*5=61..65
    float ss=0.f;
    for(int i=0;i<5;i++){ float v=tot[wave][61+i]; ss+=v*v; }
    float n = sqrtf(ss+1e-12f);
    float sc = 1.f/(1.f+expf(-n));
    op[d] = t1*sc;
  }
}

// ---------------- norm_act (fallback path only) ----------------

__global__ void norm_act_kernel(float* __restrict__ out, int total){
  int idx=blockIdx.x*blockDim.x+threadIdx.x;
  if(idx>=total) return;
  int c = idx % 26; long bn = idx / 26;
  int off, len;
  if(c<12){ off=c; len=1; }
  else if(c<16){ off=12+(c-12)*3; len=3; }
  else if(c<20){ off=24+(c-16)*3; len=3; }
  else { off=36+(c-20)*5; len=5; }
  float* p = out + bn*(long)DIM + off;
  float sum=0.f;
  for(int i=0;i<len;i++){ float v=p[i]; sum+=v*v; }
  float n = sqrtf(sum+1e-12f);
  float sc = 1.f/(1.f+expf(-n));
  for(int i=0;i<len;i++) p[i]*=sc;
}

// ---------------- launch ----------------

extern "C" void kernel_launch(void* const* d_in, const int* in_sizes, int n_in,
                              void* d_out, int out_size, void* d_ws, size_t ws_size,
                              hipStream_t stream)
{
  const float* h       = (const float*)d_in[0];
  const int*   e_src   = (const int*)  d_in[1];
  const int*   e_dst   = (const int*)  d_in[2];
  const float* e_attr  = (const float*)d_in[3];
  const float* lw0     = (const float*)d_in[4];
  const float* lw1o    = (const float*)d_in[5];
  const float* lw1e    = (const float*)d_in[6];
  const float* lw2     = (const float*)d_in[7];
  const float* lb0     = (const float*)d_in[8];
  const float* rw0     = (const float*)d_in[9];
  const float* rw1o    = (const float*)d_in[10];
  const float* rw1e    = (const float*)d_in[11];
  const float* rw2     = (const float*)d_in[12];
  const float* rb0     = (const float*)d_in[13];
  const float* rad_w1  = (const float*)d_in[14];
  const float* rad_w2  = (const float*)d_in[15];

  const int B  = 2;
  const int BE = in_sizes[1];
  const int E  = BE / B;
  const int BN = in_sizes[0] / DIM;
  const int N  = BN / B;

  float* ws   = (float*)d_ws;
  float* h_in = ws;                                   // BN*DIM f32
  float* cg   = ws + (size_t)BN*DIM;                  // 640 f32
  h2*    wf2  = (h2*)(cg + 640);                      // WNUM*16 h2
  h2*    hidg2= wf2 + (size_t)WNUM*16;                // 16*BE h2
  _Float16* msgh = (_Float16*)(hidg2 + (size_t)16*BE);// DIM*BE f16
  _Float16* msgT = msgh + (size_t)DIM*BE;             // BE*DIM f16
  int*   cnt  = (int*)(msgT + (size_t)BE*DIM);
  int*   cur  = cnt + BN;
  int*   offp = cur + BN;
  int*   elist= offp + BN;

  size_t need_f = (size_t)BN*DIM + 640 + (size_t)WNUM*16 + (size_t)16*BE
                + (size_t)DIM*BE + 3*(size_t)BN + (size_t)BE;   // (f16 pairs counted as 1 f32 each; conservative)
  bool csr_ok = (ws_size/4) >= need_f + 1024;

  cg_init_kernel<<<NPATH, 128, 0, stream>>>(cg);
  int wfn = WNUM*16;
  wf2_pack_kernel<<<(wfn+255)/256, 256, 0, stream>>>(rad_w2, wf2);
  dim3 hgrid((BE+255)/256, 16);
  hid2_kernel<<<hgrid, 256, 0, stream>>>(e_attr, rad_w1, hidg2, BE);
  int totL = BN*DIM;
  linear_kernel<<<(totL+255)/256, 256, 0, stream>>>(h, lw0, lw1o, lw1e, lw2, lb0,
                                                    rw0, rw1o, rw1e, rw2, rb0,
                                                    h_in, (float*)d_out, totL);
  if(csr_ok){
    hipMemsetAsync(cnt, 0, 2*(size_t)BN*sizeof(int), stream);   // cnt + cur
    count_kernel<<<(BE+255)/256, 256, 0, stream>>>(e_dst, cnt, BE, N, E);
    scan_kernel<<<1, 1024, 0, stream>>>(cnt, offp, BN);
    fill_kernel<<<(BE+255)/256, 256, 0, stream>>>(e_dst, offp, cur, elist, BE, N, E);
    dim3 bgrid(26, (BE+255)/256);
    tp_out_kernel<false><<<bgrid, 256, 0, stream>>>(h_in, e_src, e_dst, e_attr,
                                                    hidg2, wf2, cg, nullptr, msgh, BE, N, E);
    msg_tr_kernel<<<(BE+63)/64, 256, 0, stream>>>(msgh, msgT, BE);
    gather2_kernel<<<(BN+3)/4, 256, 0, stream>>>(msgT, cnt, offp, elist, (float*)d_out, BN);
  } else {
    dim3 bgrid(26, (BE+255)/256);
    tp_out_kernel<true><<<bgrid, 256, 0, stream>>>(h_in, e_src, e_dst, e_attr,
                                                   hidg2, wf2, cg, (float*)d_out, msgh, BE, N, E);
    int totN = BN*26;
    norm_act_kernel<<<(totN+255)/256, 256, 0, stream>>>((float*)d_out, totN);
  }
}